// Round 3
// baseline (240.227 us; speedup 1.0000x reference)
//
#include <hip/hip_runtime.h>
#include <hip/hip_bf16.h>
#include <hip/hip_fp16.h>

#define S_LEN 2048
#define E_DIM 2048
#define H_NUM 32
#define D_DIM 64

typedef __attribute__((ext_vector_type(8))) short short8;
typedef __attribute__((ext_vector_type(4))) short short4v;
typedef __attribute__((ext_vector_type(4))) float f32x4;
typedef __attribute__((ext_vector_type(4))) int i32x4;

__device__ __forceinline__ unsigned short f2h(float f) {
  return __builtin_bit_cast(unsigned short, (_Float16)f);
}

__device__ __forceinline__ float h2f(unsigned short u) {
  return (float)__builtin_bit_cast(_Float16, u);
}

__device__ __forceinline__ float fq1(float x, float invs, float scale) {
  return fminf(fmaxf(rintf(x * invs), -128.f), 127.f) * scale;
}

__device__ __forceinline__ int q8(float x, float invs) {
  return min(max((int)rintf(x * invs), -128), 127);
}

__device__ __forceinline__ void gload_lds16(const void* g, void* l) {
  __builtin_amdgcn_global_load_lds((const __attribute__((address_space(1))) void*)g,
                                   (__attribute__((address_space(3))) void*)l, 16, 0, 0);
}

__device__ __forceinline__ f32x4 mfma16h(short8 a, short8 b, f32x4 c) {
  return __builtin_amdgcn_mfma_f32_16x16x32_f16(a, b, c, 0, 0, 0);
}

__device__ __forceinline__ i32x4 mfma16i8(i32x4 a, i32x4 b, i32x4 c) {
  return __builtin_amdgcn_mfma_i32_16x16x64_i8(a, b, c, 0, 0, 0);
}

#define VMW4() asm volatile("s_waitcnt vmcnt(4)" ::: "memory")
#define VMW3() asm volatile("s_waitcnt vmcnt(3)" ::: "memory")
#define VMW0() asm volatile("s_waitcnt vmcnt(0)" ::: "memory")
#define BARR() asm volatile("s_barrier" ::: "memory")
#define LGKM0() asm volatile("s_waitcnt lgkmcnt(0)" ::: "memory")

// ========= merged prologue: cvt + quant_w + quant_wo + sc init + RoPE table =========
// blocks [0,4096): hs cvt; [4096,10240): w_{q,k,v}; [10240,12288): w_o->i8;
// b==12288: sc init; [12289,12545): cos/sin table (65536 (s,i) pairs, f32x2).
__global__ void k_prep(const float* __restrict__ hs,
                       const float* __restrict__ w_q, const float* __restrict__ w_k,
                       const float* __restrict__ w_v, const float* __restrict__ w_o,
                       unsigned short* __restrict__ hsb, unsigned short* __restrict__ wq_all,
                       signed char* __restrict__ wo_i8, float* __restrict__ wsc,
                       unsigned* __restrict__ sc, float2* __restrict__ trig) {
  const int b = blockIdx.x;
  if (b < 4096) {
    int i = b * 256 + threadIdx.x;
    float4 v = ((const float4*)hs)[i];
    ushort4 r;
    r.x = f2h(v.x); r.y = f2h(v.y); r.z = f2h(v.z); r.w = f2h(v.w);
    ((ushort4*)hsb)[i] = r;
    return;
  }
  if (b >= 12288) {
    if (b == 12288) {
      if (threadIdx.x < 8) sc[threadIdx.x] = 0u;
      return;
    }
    // trig table: idx = (b-12289)*256 + tid -> s = idx>>5, i = idx&31
    int idx = (b - 12289) * 256 + threadIdx.x;
    int s = idx >> 5, i = idx & 31;
    float freq = exp2f(-(float)i * (13.287712379549449f / 32.f));
    float ang = (float)s * freq;
    float sn, cs;
    sincosf(ang, &sn, &cs);
    float2 t; t.x = cs; t.y = sn;
    trig[idx] = t;
    return;
  }
  __shared__ float wm[4];
  const int isWo = (b >= 10240);
  const int bb = isWo ? (b - 10240) : (b - 4096);
  const int wy = isWo ? 0 : (bb >> 11);
  const int wx = isWo ? bb : (bb & 2047);
  const float* w = isWo ? w_o : (wy == 0 ? w_q : wy == 1 ? w_k : w_v);
  const float* row = w + (size_t)wx * E_DIM;
  float4 a = ((const float4*)row)[threadIdx.x * 2];
  float4 bq = ((const float4*)row)[threadIdx.x * 2 + 1];
  float m = fmaxf(fmaxf(fmaxf(fabsf(a.x), fabsf(a.y)), fmaxf(fabsf(a.z), fabsf(a.w))),
                  fmaxf(fmaxf(fabsf(bq.x), fabsf(bq.y)), fmaxf(fabsf(bq.z), fabsf(bq.w))));
#pragma unroll
  for (int off = 32; off; off >>= 1) m = fmaxf(m, __shfl_xor(m, off));
  if ((threadIdx.x & 63) == 0) wm[threadIdx.x >> 6] = m;
  __syncthreads();
  m = fmaxf(fmaxf(wm[0], wm[1]), fmaxf(wm[2], wm[3]));
  float scale = fmaxf(m * (1.f / 127.f), 1e-8f);
  float invs = 1.f / scale;
  if (isWo) {
    unsigned lo = (unsigned)(q8(a.x, invs) & 255) | ((unsigned)(q8(a.y, invs) & 255) << 8) |
                  ((unsigned)(q8(a.z, invs) & 255) << 16) | ((unsigned)(q8(a.w, invs) & 255) << 24);
    unsigned hi = (unsigned)(q8(bq.x, invs) & 255) | ((unsigned)(q8(bq.y, invs) & 255) << 8) |
                  ((unsigned)(q8(bq.z, invs) & 255) << 16) | ((unsigned)(q8(bq.w, invs) & 255) << 24);
    uint2 pk; pk.x = lo; pk.y = hi;
    ((uint2*)(wo_i8 + (size_t)wx * E_DIM))[threadIdx.x] = pk;
    if (threadIdx.x == 0) wsc[wx] = scale;
  } else {
    unsigned short* orow = wq_all + (size_t)wy * E_DIM * E_DIM + (size_t)wx * E_DIM;
    ushort4 r0, r1;
    r0.x = f2h(fq1(a.x, invs, scale)); r0.y = f2h(fq1(a.y, invs, scale));
    r0.z = f2h(fq1(a.z, invs, scale)); r0.w = f2h(fq1(a.w, invs, scale));
    r1.x = f2h(fq1(bq.x, invs, scale)); r1.y = f2h(fq1(bq.y, invs, scale));
    r1.z = f2h(fq1(bq.z, invs, scale)); r1.w = f2h(fq1(bq.w, invs, scale));
    ((ushort4*)orow)[threadIdx.x * 2] = r0;
    ((ushort4*)orow)[threadIdx.x * 2 + 1] = r1;
  }
}

// ========= 256x192 8-phase double-buffered f16 GEMM (N-fused QKV), XCD-swizzled =====
// N_total = 3*2048 = 6144 fused; grid = 8 (M) x 32 (N) = 256 blocks (ALL CUs).
// 512 threads = 8 waves (2M x 4N), wave-tile 128x48, BK=64 (2 K-steps/tile).
// LDS 112 KiB: buf(56KB) = [A s0 16K][A s1 16K][B s0 12K][B s1 12K], row 64B,
// chunk swizzle cc ^= (row>>1)&3 applied on global src (linear LDS dest).
// Staging of tile t+1 spread over ph1(A s0), ph2(B s0), ph3(A s1), ph4(B s1);
// counted vmcnt(3) at ph2/ph4 end (R0 discipline, never drained in-loop).
// B chunk = 12KB -> waves 0-3 issue the extra load; vmcnt(3) correct for both
// wave groups (exact drain for 6-load waves, +1 landed-long-ago for 8-load).
__global__ __launch_bounds__(512, 2)
void k_gemm_qkv(const unsigned short* __restrict__ A, const unsigned short* __restrict__ Bt,
                unsigned short* __restrict__ C, unsigned* __restrict__ amax, float alpha_q) {
  __shared__ char lds[114688];
  const int K = 2048, NT = 32;
  // bijective XCD swizzle: 256 wgs, 32 per XCD; each XCD owns one ibx (A panel
  // 1MB -> L2-resident) x all 32 iby.
  const int lin = blockIdx.x;
  const int swz = (lin & 7) * 32 + (lin >> 3);
  const int ibx = swz >> 5;
  const int iby = swz & 31;

  const int tid = threadIdx.x;
  const int wv = tid >> 6, ln = tid & 63;
  const int wm = wv >> 2, wn = wv & 3;
  const size_t bm = (size_t)ibx * 256, bn = (size_t)iby * 192;
  const int arow = ln & 15, gsl = ln >> 4;

  // LDS read byte offsets within one 56KB buffer (A k-step: +16384; B: +12288)
  int abyte[8], bbyte[3];
#pragma unroll
  for (int i = 0; i < 8; ++i) {
    int r = wm * 128 + i * 16 + arow;
    abyte[i] = r * 64 + ((gsl ^ ((r >> 1) & 3)) * 16);
  }
#pragma unroll
  for (int j = 0; j < 3; ++j) {
    int r = wn * 48 + j * 16 + arow;
    bbyte[j] = 32768 + r * 64 + ((gsl ^ ((r >> 1) & 3)) * 16);
  }

  // staging: thread tid covers row (tid>>2) [+128] of a 256(192)x32 chunk;
  // pre-swizzled global source col-chunk so linear LDS dest + swizzled read agree
  const int srow = tid >> 2;
  const int scc = (tid & 3) ^ ((tid >> 3) & 3);
  const unsigned short* Asrc = A + (bm + srow) * (size_t)K + scc * 8;
  const unsigned short* Bsrc = Bt + (bn + srow) * (size_t)K + scc * 8;
  const int ldst = tid * 16;

#define BUFOF(T) (((T) & 1) * 57344)
#define STGA(T, S) do { \
    char* d_ = lds + BUFOF(T) + (S) * 16384 + ldst; \
    const unsigned short* s_ = Asrc + (T) * 64 + (S) * 32; \
    gload_lds16(s_, d_); \
    gload_lds16(s_ + (size_t)128 * K, d_ + 8192); } while (0)
#define STGB(T, S) do { \
    char* d_ = lds + BUFOF(T) + 32768 + (S) * 12288 + ldst; \
    const unsigned short* s_ = Bsrc + (T) * 64 + (S) * 32; \
    gload_lds16(s_, d_); \
    if (tid < 256) gload_lds16(s_ + (size_t)128 * K, d_ + 8192); } while (0)

  f32x4 acc[8][3];
#pragma unroll
  for (int i = 0; i < 8; ++i)
#pragma unroll
    for (int j = 0; j < 3; ++j) { acc[i][j][0] = 0.f; acc[i][j][1] = 0.f; acc[i][j][2] = 0.f; acc[i][j][3] = 0.f; }

  // prologue: stage all of tile 0, drain (prologue only), barrier
  STGA(0, 0); STGB(0, 0); STGA(0, 1); STGB(0, 1);
  VMW0();
  BARR();

  // One K-tile = 4 phases x 12 MFMA.
#define TILE(BUF, DS, T1, W2X, W4X) do { \
    char* bp_ = lds + (BUF); \
    short8 af_[4], bf_[3], ag_[4]; \
    /* ---- phase 1: i0..3 x j0..2, k-step 0; stage A(t+1) s0 ---- */ \
    _Pragma("unroll") for (int i = 0; i < 4; ++i) af_[i] = *(const short8*)(bp_ + abyte[i]); \
    _Pragma("unroll") for (int j = 0; j < 3; ++j) bf_[j] = *(const short8*)(bp_ + bbyte[j]); \
    if (DS) STGA(T1, 0); \
    BARR(); LGKM0(); \
    __builtin_amdgcn_s_setprio(1); \
    _Pragma("unroll") for (int i = 0; i < 4; ++i) \
      _Pragma("unroll") for (int j = 0; j < 3; ++j) acc[i][j] = mfma16h(af_[i], bf_[j], acc[i][j]); \
    __builtin_amdgcn_s_setprio(0); \
    BARR(); \
    /* ---- phase 2: i4..7 x j0..2, k-step 0; stage B(t+1) s0 ---- */ \
    _Pragma("unroll") for (int i = 0; i < 4; ++i) ag_[i] = *(const short8*)(bp_ + abyte[4 + i]); \
    if (DS) STGB(T1, 0); \
    BARR(); LGKM0(); \
    __builtin_amdgcn_s_setprio(1); \
    _Pragma("unroll") for (int i = 0; i < 4; ++i) \
      _Pragma("unroll") for (int j = 0; j < 3; ++j) acc[4 + i][j] = mfma16h(ag_[i], bf_[j], acc[4 + i][j]); \
    __builtin_amdgcn_s_setprio(0); \
    W2X; \
    BARR(); \
    /* ---- phase 3: i0..3 x j0..2, k-step 1; stage A(t+1) s1 ---- */ \
    _Pragma("unroll") for (int i = 0; i < 4; ++i) af_[i] = *(const short8*)(bp_ + 16384 + abyte[i]); \
    _Pragma("unroll") for (int j = 0; j < 3; ++j) bf_[j] = *(const short8*)(bp_ + 12288 + bbyte[j]); \
    if (DS) STGA(T1, 1); \
    BARR(); LGKM0(); \
    __builtin_amdgcn_s_setprio(1); \
    _Pragma("unroll") for (int i = 0; i < 4; ++i) \
      _Pragma("unroll") for (int j = 0; j < 3; ++j) acc[i][j] = mfma16h(af_[i], bf_[j], acc[i][j]); \
    __builtin_amdgcn_s_setprio(0); \
    BARR(); \
    /* ---- phase 4: i4..7 x j0..2, k-step 1; stage B(t+1) s1 ---- */ \
    _Pragma("unroll") for (int i = 0; i < 4; ++i) ag_[i] = *(const short8*)(bp_ + 16384 + abyte[4 + i]); \
    if (DS) STGB(T1, 1); \
    BARR(); LGKM0(); \
    __builtin_amdgcn_s_setprio(1); \
    _Pragma("unroll") for (int i = 0; i < 4; ++i) \
      _Pragma("unroll") for (int j = 0; j < 3; ++j) acc[4 + i][j] = mfma16h(ag_[i], bf_[j], acc[4 + i][j]); \
    __builtin_amdgcn_s_setprio(0); \
    W4X; \
    BARR(); \
  } while (0)

#pragma unroll 1
  for (int t = 0; t < NT - 2; t += 2) {
    TILE(0, 1, t + 1, VMW3(), VMW3());
    TILE(57344, 1, t + 2, VMW3(), VMW3());
  }
  TILE(0, 1, NT - 1, VMW3(), VMW3());
  TILE(57344, 0, 0, VMW0(), (void)0);
#undef TILE
#undef STGA
#undef STGB
#undef BUFOF

  // epilogue: per-j z (16-col fragments never straddle the 2048 boundary)
#pragma unroll
  for (int j = 0; j < 3; ++j) {
    const int colbase = (int)bn + wn * 48 + j * 16;  // wave-uniform
    const int zj = colbase >> 11;
    const float alpha = (zj == 0) ? alpha_q : 1.0f;
    unsigned short* Cz = C + (size_t)zj * S_LEN * E_DIM;
    const int col = (colbase & 2047) + arow;
    float amxj = 0.f;
#pragma unroll
    for (int i = 0; i < 8; ++i) {
      size_t rowb = bm + wm * 128 + i * 16 + gsl * 4;
#pragma unroll
      for (int r = 0; r < 4; ++r) {
        float v = acc[i][j][r] * alpha;
        Cz[(rowb + r) * E_DIM + col] = f2h(v);
        amxj = fmaxf(amxj, fabsf(v));
      }
    }
#pragma unroll
    for (int off = 32; off; off >>= 1) amxj = fmaxf(amxj, __shfl_xor(amxj, off));
    if (ln == 0) atomicMax(amax + zj, __float_as_uint(amxj));
  }
}

// ========= o-proj: 128x64 tri-buffered INT8 GEMM, XCD-swizzled =========
__global__ __launch_bounds__(256, 4)
void k_gemm_o(const signed char* __restrict__ A, const signed char* __restrict__ Bt,
              float* __restrict__ C, const unsigned* __restrict__ sc,
              const float* __restrict__ wsc) {
  __shared__ char lds[36864];
  const int K = 2048, NT = 32;
  const float sa = fmaxf(__uint_as_float(sc[3]) * (1.f / 127.f), 1e-8f);
  const int lin = blockIdx.y * 16 + blockIdx.x;
  const int swz = (lin & 7) * 64 + (lin >> 3);
  const int iby = swz >> 4;
  const int ibx = swz & 15;

  const int tid = threadIdx.x;
  const int wv = tid >> 6, ln = tid & 63;
  const int wm = wv >> 1, wn = wv & 1;
  const size_t bm = (size_t)ibx * 128, bn = (size_t)iby * 64;
  const int arow = ln & 15, gsl = ln >> 4;

  int abyte[4], bbyte[2];
#pragma unroll
  for (int i = 0; i < 4; ++i) {
    int ra = wm * 64 + i * 16 + arow;
    abyte[i] = ra * 64 + ((gsl ^ ((ra >> 1) & 3)) * 16);
  }
#pragma unroll
  for (int j = 0; j < 2; ++j) {
    int rb = wn * 32 + j * 16 + arow;
    bbyte[j] = rb * 64 + ((gsl ^ ((rb >> 1) & 3)) * 16);
  }

  const int srow = tid >> 2;
  const int sl = (tid & 3) ^ ((srow >> 1) & 3);
  const signed char* Ast = A + (bm + srow) * (size_t)K + sl * 16;
  const signed char* Bst = Bt + (bn + srow) * (size_t)K + sl * 16;

#define STG(T, dst) do { if ((T) < NT) { \
    size_t go = (size_t)(T) * 64; \
    gload_lds16(Ast + go, (dst) + wv * 1024); \
    gload_lds16(Ast + go + (size_t)64 * K, (dst) + 4096 + wv * 1024); \
    gload_lds16(Bst + go, (dst) + 8192 + wv * 1024); } } while (0)

  i32x4 acc[4][2];
#pragma unroll
  for (int i = 0; i < 4; ++i)
#pragma unroll
    for (int j = 0; j < 2; ++j) { acc[i][j][0] = 0; acc[i][j][1] = 0; acc[i][j][2] = 0; acc[i][j][3] = 0; }

  char* b0 = lds;
  char* b1 = lds + 12288;
  char* b2 = lds + 24576;

  STG(0, b0); STG(1, b1);
  VMW3();
  BARR();

#define ITER(T, bufR, bufS) do { \
    i32x4 af[4], bf[2]; \
    _Pragma("unroll") \
    for (int i = 0; i < 4; ++i) af[i] = *(const i32x4*)((bufR) + abyte[i]); \
    _Pragma("unroll") \
    for (int j = 0; j < 2; ++j) bf[j] = *(const i32x4*)((bufR) + 8192 + bbyte[j]); \
    STG((T) + 2, bufS); \
    __builtin_amdgcn_s_setprio(1); \
    _Pragma("unroll") \
    for (int i = 0; i < 4; ++i) \
      _Pragma("unroll") \
      for (int j = 0; j < 2; ++j) acc[i][j] = mfma16i8(af[i], bf[j], acc[i][j]); \
    __builtin_amdgcn_s_setprio(0); \
    if ((T) == NT - 2) { VMW0(); } else if ((T) < NT - 2) { VMW3(); } \
    BARR(); } while (0)

#pragma unroll 1
  for (int t = 0; t + 2 < NT; t += 3) {
    ITER(t, b0, b2);
    ITER(t + 1, b1, b0);
    ITER(t + 2, b2, b1);
  }
  ITER(NT - 2, b0, b2);
  ITER(NT - 1, b1, b0);
#undef ITER
#undef STG

#pragma unroll
  for (int i = 0; i < 4; ++i) {
    size_t rowb = bm + wm * 64 + i * 16 + gsl * 4;
#pragma unroll
    for (int j = 0; j < 2; ++j) {
      size_t col = bn + wn * 32 + j * 16 + arow;
      float s = sa * wsc[col];
#pragma unroll
      for (int r = 0; r < 4; ++r)
        C[(rowb + r) * E_DIM + col] = (float)acc[i][j][r] * s;
    }
  }
}

// ========= merged RoPE(q,k, table-driven) + V-transpose (f16 in/out) =========
__global__ void k_rvt(const unsigned short* __restrict__ qkv,
                      unsigned short* __restrict__ Qh, unsigned short* __restrict__ Kh,
                      unsigned short* __restrict__ Vt, const unsigned* __restrict__ sc,
                      const float2* __restrict__ trig) {
  __shared__ float tb[64][65];
  const int z = blockIdx.z;
  if (z < 2) {
    const unsigned short* x = qkv + (z ? 4194304 : 0);
    unsigned short* out = z ? Kh : Qh;
    float scale = fmaxf(__uint_as_float(sc[z]) * (1.f / 127.f), 1e-8f);
    float invs = 1.f / scale;
    int h = blockIdx.y;
    int s = blockIdx.x * 8 + (threadIdx.x >> 5);
    int i = threadIdx.x & 31;
    size_t base = (size_t)s * E_DIM + h * 64 + i;
    float x0 = h2f(x[base]);
    float x1 = h2f(x[base + 32]);
    float q0 = fq1(x0, invs, scale);
    float q1 = fq1(x1, invs, scale);
    float2 t = trig[s * 32 + i];
    size_t ob = (size_t)h * S_LEN * D_DIM + (size_t)s * D_DIM + i;
    out[ob] = f2h(q0 * t.x - q1 * t.y);
    out[ob + 32] = f2h(q1 * t.x + q0 * t.y);
    return;
  }
  if (blockIdx.x >= 32) return;
  const unsigned short* v = qkv + 2 * 4194304;
  float scale = fmaxf(__uint_as_float(sc[2]) * (1.f / 127.f), 1e-8f);
  float invs = 1.f / scale;
  int s0 = blockIdx.x * 64, h = blockIdx.y;
#pragma unroll
  for (int l = 0; l < 16; ++l) {
    int idx = threadIdx.x + l * 256;
    int r = idx >> 6, c = idx & 63;
    float x = h2f(v[(size_t)(s0 + r) * E_DIM + h * 64 + c]);
    tb[r][c] = fq1(x, invs, scale);
  }
  __syncthreads();
#pragma unroll
  for (int l = 0; l < 16; ++l) {
    int idx = threadIdx.x + l * 256;
    int d = idx >> 6, s = idx & 63;
    Vt[(size_t)h * D_DIM * S_LEN + (size_t)d * S_LEN + s0 + s] = f2h(tb[s][d]);
  }
}

// -------- causal flash attention: 40KB LDS -> 4 blocks/CU (16 waves/CU) --------
__global__ __launch_bounds__(256, 4)
void k_attn(const unsigned short* __restrict__ Qh, const unsigned short* __restrict__ Kh,
            const unsigned short* __restrict__ Vt, unsigned short* __restrict__ att,
            unsigned* __restrict__ amax) {
  __shared__ char Kbuf[2 * 8192];
  __shared__ char Vbuf[2 * 8192];
  __shared__ __align__(16) char Pb[8192];
  const int L = blockIdx.x;
  const int h = L & 31;
  const int qc = 31 - (L >> 5);
  const int nt = qc + 1;
  const int tid = threadIdx.x;
  const int wv = tid >> 6, ln = tid & 63;
  const int arow = ln & 15, gsl = ln >> 4;
  const unsigned short* Qb = Qh + (size_t)h * S_LEN * D_DIM;
  const unsigned short* Kb = Kh + (size_t)h * S_LEN * D_DIM;
  const unsigned short* Vb = Vt + (size_t)h * D_DIM * S_LEN;
  const int qr = qc * 64 + wv * 16;

  const int srow0 = tid >> 3, sch0 = (tid & 7) ^ (srow0 & 7);
  const int srow1 = 32 + (tid >> 3), sch1 = (tid & 7) ^ (srow1 & 7);

#define STAGEK(T, B) do { char* kd = Kbuf + (B) * 8192; const int tb_ = (T) * 64; \
    gload_lds16(Kb + (size_t)(tb_ + srow0) * D_DIM + sch0 * 8, kd + wv * 1024); \
    gload_lds16(Kb + (size_t)(tb_ + srow1) * D_DIM + sch1 * 8, kd + 4096 + wv * 1024); } while (0)
#define STAGEV(T, B) do { char* vd = Vbuf + (B) * 8192; const int tb_ = (T) * 64; \
    gload_lds16(Vb + (size_t)srow0 * S_LEN + tb_ + sch0 * 8, vd + wv * 1024); \
    gload_lds16(Vb + (size_t)srow1 * S_LEN + tb_ + sch1 * 8, vd + 4096 + wv * 1024); } while (0)

  short8 qa0 = *(const short8*)(Qb + (size_t)(qr + arow) * D_DIM + gsl * 8);
  short8 qa1 = *(const short8*)(Qb + (size_t)(qr + arow) * D_DIM + 32 + gsl * 8);

  f32x4 o[4];
  float mrow = -INFINITY, lrow = 0.f;
#pragma unroll
  for (int d = 0; d < 4; ++d) { o[d][0] = 0.f; o[d][1] = 0.f; o[d][2] = 0.f; o[d][3] = 0.f; }

  STAGEK(0, 0);
  STAGEV(0, 0);
  if (nt > 1) { STAGEK(1, 1); STAGEV(1, 1); VMW4(); } else { VMW0(); }
  BARR();

  char* Pw = Pb + wv * 2048 + arow * 128;
  const int arw7 = arow & 7;

#pragma unroll 1
  for (int t = 0; t < nt; ++t) {
    if (t >= 1 && t + 1 < nt) { STAGEK(t + 1, (t + 1) & 1); STAGEV(t + 1, (t + 1) & 1); }
    char* kb = Kbuf + (t & 1) * 8192;
    char* vb = Vbuf + (t & 1) * 8192;

    short8 kf[4][2];
#pragma unroll
    for (int kvb = 0; kvb < 4; ++kvb) {
      int row = kvb * 16 + arow;
      int sw = (row & 7) << 4;
      kf[kvb][0] = *(const short8*)(kb + row * 128 + ((gsl * 16) ^ sw));
      kf[kvb][1] = *(const short8*)(kb + row * 128 + ((64 + gsl * 16) ^ sw));
    }
    f32x4 s4[4];
#pragma unroll
    for (int kvb = 0; kvb < 4; ++kvb) {
      s4[kvb][0] = 0.f; s4[kvb][1] = 0.f; s4[kvb][2] = 0.f; s4[kvb][3] = 0.f;
    }
#pragma unroll
    for (int kvb = 0; kvb < 4; ++kvb) {
      s4[kvb] = mfma16h(kf[kvb][0], qa0, s4[kvb]);
      s4[kvb] = mfma16h(kf[kvb][1], qa1, s4[kvb]);
    }

    const int t0 = t * 64;
    const int qrow = qr + arow;
    if (t0 + 63 > qrow) {
#pragma unroll
      for (int kvb = 0; kvb < 4; ++kvb) {
        int colb = t0 + kvb * 16 + gsl * 4;
#pragma unroll
        for (int r = 0; r < 4; ++r)
          if (colb + r > qrow) s4[kvb][r] = -INFINITY;
      }
    }

    float smax = s4[0][0];
#pragma unroll
    for (int kvb = 0; kvb < 4; ++kvb)
#pragma unroll
      for (int r = 0; r < 4; ++r) smax = fmaxf(smax, s4[kvb][r]);
    smax = fmaxf(smax, __shfl_xor(smax, 16));
    smax = fmaxf(smax, __shfl_xor(smax, 32));

    float mn = fmaxf(mrow, smax);
    float corr = __expf(mrow - mn);
    mrow = mn;

    float rs = 0.f;
    float p[4][4];
#pragma unroll
    for (int kvb = 0; kvb < 4; ++kvb)
#pragma unroll
      for (int r = 0; r < 4; ++r) {
        p[kvb][r] = __expf(s4[kvb][r] - mn);
        rs += p[kvb][r];
      }
    rs += __shfl_xor(rs, 16);
    rs += __shfl_xor(rs, 32);
    lrow = lrow * corr + rs;

    float corr_r[4];
#pragma unroll
    for (int r = 0; r < 4; ++r) corr_r[r] = __shfl(corr, gsl * 4 + r);
#pragma unroll
    for (int d = 0; d < 4; ++d)
#pragma unroll
      for (int r = 0; r < 4; ++r) o[d][r] *= corr_r[r];

    __builtin_amdgcn_wave_barrier();
#pragma unroll
    for (int kvb = 0; kvb < 4; ++kvb) {
      short4v pw;
      pw[0] = (short)f2h(p[kvb][0]);
      pw[1] = (short)f2h(p[kvb][1]);
      pw[2] = (short)f2h(p[kvb][2]);
      pw[3] = (short)f2h(p[kvb][3]);
      const int u = kvb * 2 + (gsl >> 1);
      *(short4v*)(Pw + ((u ^ arw7) << 4) + ((gsl & 1) << 3)) = pw;
    }
    __builtin_amdgcn_wave_barrier();
    short8 pa0 = *(const short8*)(Pw + ((gsl ^ arw7) << 4));
    short8 pa1 = *(const short8*)(Pw + (((4 + gsl) ^ arw7) << 4));
    __builtin_amdgcn_wave_barrier();

    short8 vf[4][2];
#pragma unroll
    for (int d = 0; d < 4; ++d) {
      int row = d * 16 + arow;
      int sw = (row & 7) << 4;
      vf[d][0] = *(const short8*)(vb + row * 128 + ((gsl * 16) ^ sw));
      vf[d][1] = *(const short8*)(vb + row * 128 + ((64 + gsl * 16) ^ sw));
    }
#pragma unroll
    for (int d = 0; d < 4; ++d) {
      o[d] = mfma16h(pa0, vf[d][0], o[d]);
      o[d] = mfma16h(pa1, vf[d][1], o[d]);
    }

    VMW0();
    BARR();
  }
#undef STAGEK
#undef STAGEV

  float amx = 0.f;
  float invl = 1.f / lrow;
  float invl_r[4];
#pragma unroll
  for (int r = 0; r < 4; ++r) invl_r[r] = __shfl(invl, gsl * 4 + r);
#pragma unroll
  for (int r = 0; r < 4; ++r) {
    size_t row = (size_t)(qr + gsl * 4 + r);
#pragma unroll
    for (int d = 0; d < 4; ++d) {
      float v = o[d][r] * invl_r[r];
      att[row * E_DIM + h * 64 + d * 16 + arow] = f2h(v);
      amx = fmaxf(amx, fabsf(v));
    }
  }

#pragma unroll
  for (int off = 32; off; off >>= 1) amx = fmaxf(amx, __shfl_xor(amx, off));
  if (ln == 0) atomicMax(amax + 3, __float_as_uint(amx));
}

// ---------------- act fake-quant f16 -> packed int8 (8 elems/thread) ----------------
__global__ void k_quant_act_i8(const unsigned short* __restrict__ in, uint2* __restrict__ out,
                               const unsigned* __restrict__ sc, int idx) {
  float scale = fmaxf(__uint_as_float(sc[idx]) * (1.f / 127.f), 1e-8f);
  float invs = 1.f / scale;
  int i = blockIdx.x * blockDim.x + threadIdx.x;
  short8 v = ((const short8*)in)[i];
  unsigned lo = 0, hi = 0;
#pragma unroll
  for (int e = 0; e < 4; ++e)
    lo |= (unsigned)(q8(h2f((unsigned short)v[e]), invs) & 255) << (8 * e);
#pragma unroll
  for (int e = 0; e < 4; ++e)
    hi |= (unsigned)(q8(h2f((unsigned short)v[4 + e]), invs) & 255) << (8 * e);
  uint2 pk; pk.x = lo; pk.y = hi;
  out[i] = pk;
}

extern "C" void kernel_launch(void* const* d_in, const int* in_sizes, int n_in,
                              void* d_out, int out_size, void* d_ws, size_t ws_size,
                              hipStream_t stream) {
  const float* hs = (const float*)d_in[0];
  const float* w_q = (const float*)d_in[1];
  const float* w_k = (const float*)d_in[2];
  const float* w_v = (const float*)d_in[3];
  const float* w_o = (const float*)d_in[4];

  char* ws = (char*)d_ws;
  unsigned short* wq_all = (unsigned short*)(ws);                 // 3 x E*E f16 (q,k,v)
  signed char* wo_i8 = (signed char*)(ws + 25165824);             // E*E i8
  float* wsc = (float*)(ws + 29360128);                           // 2048 f32
  float2* trig = (float2*)(ws + 30408704);                        // 65536 float2 (512KB)
  unsigned short* hsb = (unsigned short*)(ws + 33554432);         // S*E f16
  unsigned short* qkv16 = (unsigned short*)(ws + 41943040);       // 3 x S*E f16
  unsigned short* att = qkv16;                                    // alias q slab (f16)
  signed char* aq_i8 = (signed char*)(ws + 67108864);             // S*E i8
  unsigned short* Qh = (unsigned short*)(ws + 92274688);          // [H][S][D] f16
  unsigned short* Kh = (unsigned short*)(ws + 100663296);
  unsigned short* Vt = (unsigned short*)(ws + 109051904);         // [H][D][S] f16
  unsigned* sc = (unsigned*)(ws + 117440512);                     // absmax scalars

  k_prep<<<12545, 256, 0, stream>>>(hs, w_q, w_k, w_v, w_o, hsb, wq_all, wo_i8, wsc, sc, trig);
  k_gemm_qkv<<<dim3(256), 512, 0, stream>>>(hsb, wq_all, qkv16, sc, 0.125f);
  k_rvt<<<dim3(256, 32, 3), 256, 0, stream>>>(qkv16, Qh, Kh, Vt, sc, trig);
  k_attn<<<1024, 256, 0, stream>>>(Qh, Kh, Vt, att, sc);
  k_quant_act_i8<<<2048, 256, 0, stream>>>(att, (uint2*)aq_i8, sc, 3);
  k_gemm_o<<<dim3(16, 32), 256, 0, stream>>>(aq_i8, wo_i8, (float*)d_out, sc, wsc);
}

// Round 4
// 238.651 us; speedup vs baseline: 1.0066x; 1.0066x over previous
//
#include <hip/hip_runtime.h>
#include <hip/hip_bf16.h>
#include <hip/hip_fp16.h>

#define S_LEN 2048
#define E_DIM 2048
#define H_NUM 32
#define D_DIM 64

typedef __attribute__((ext_vector_type(8))) short short8;
typedef __attribute__((ext_vector_type(4))) short short4v;
typedef __attribute__((ext_vector_type(4))) float f32x4;
typedef __attribute__((ext_vector_type(4))) int i32x4;

__device__ __forceinline__ unsigned short f2h(float f) {
  return __builtin_bit_cast(unsigned short, (_Float16)f);
}

__device__ __forceinline__ float h2f(unsigned short u) {
  return (float)__builtin_bit_cast(_Float16, u);
}

__device__ __forceinline__ float fq1(float x, float invs, float scale) {
  return fminf(fmaxf(rintf(x * invs), -128.f), 127.f) * scale;
}

__device__ __forceinline__ int q8(float x, float invs) {
  return min(max((int)rintf(x * invs), -128), 127);
}

__device__ __forceinline__ void gload_lds16(const void* g, void* l) {
  __builtin_amdgcn_global_load_lds((const __attribute__((address_space(1))) void*)g,
                                   (__attribute__((address_space(3))) void*)l, 16, 0, 0);
}

__device__ __forceinline__ f32x4 mfma16h(short8 a, short8 b, f32x4 c) {
  return __builtin_amdgcn_mfma_f32_16x16x32_f16(a, b, c, 0, 0, 0);
}

__device__ __forceinline__ i32x4 mfma16i8(i32x4 a, i32x4 b, i32x4 c) {
  return __builtin_amdgcn_mfma_i32_16x16x64_i8(a, b, c, 0, 0, 0);
}

#define VMW4() asm volatile("s_waitcnt vmcnt(4)" ::: "memory")
#define VMW3() asm volatile("s_waitcnt vmcnt(3)" ::: "memory")
#define VMW0() asm volatile("s_waitcnt vmcnt(0)" ::: "memory")
#define BARR() asm volatile("s_barrier" ::: "memory")
#define LGKM0() asm volatile("s_waitcnt lgkmcnt(0)" ::: "memory")

// ========= merged prologue: cvt + quant_w + quant_wo + sc init + RoPE table =========
// blocks [0,4096): hs cvt; [4096,10240): w_{q,k,v}; [10240,12288): w_o->i8;
// b==12288: sc init; [12289,12545): cos/sin table (65536 (s,i) pairs, f32x2).
__global__ void k_prep(const float* __restrict__ hs,
                       const float* __restrict__ w_q, const float* __restrict__ w_k,
                       const float* __restrict__ w_v, const float* __restrict__ w_o,
                       unsigned short* __restrict__ hsb, unsigned short* __restrict__ wq_all,
                       signed char* __restrict__ wo_i8, float* __restrict__ wsc,
                       unsigned* __restrict__ sc, float2* __restrict__ trig) {
  const int b = blockIdx.x;
  if (b < 4096) {
    int i = b * 256 + threadIdx.x;
    float4 v = ((const float4*)hs)[i];
    ushort4 r;
    r.x = f2h(v.x); r.y = f2h(v.y); r.z = f2h(v.z); r.w = f2h(v.w);
    ((ushort4*)hsb)[i] = r;
    return;
  }
  if (b >= 12288) {
    if (b == 12288) {
      if (threadIdx.x < 8) sc[threadIdx.x] = 0u;
      return;
    }
    // trig table: idx = (b-12289)*256 + tid -> s = idx>>5, i = idx&31
    int idx = (b - 12289) * 256 + threadIdx.x;
    int s = idx >> 5, i = idx & 31;
    float freq = exp2f(-(float)i * (13.287712379549449f / 32.f));
    float ang = (float)s * freq;
    float sn, cs;
    sincosf(ang, &sn, &cs);
    float2 t; t.x = cs; t.y = sn;
    trig[idx] = t;
    return;
  }
  __shared__ float wm[4];
  const int isWo = (b >= 10240);
  const int bb = isWo ? (b - 10240) : (b - 4096);
  const int wy = isWo ? 0 : (bb >> 11);
  const int wx = isWo ? bb : (bb & 2047);
  const float* w = isWo ? w_o : (wy == 0 ? w_q : wy == 1 ? w_k : w_v);
  const float* row = w + (size_t)wx * E_DIM;
  float4 a = ((const float4*)row)[threadIdx.x * 2];
  float4 bq = ((const float4*)row)[threadIdx.x * 2 + 1];
  float m = fmaxf(fmaxf(fmaxf(fabsf(a.x), fabsf(a.y)), fmaxf(fabsf(a.z), fabsf(a.w))),
                  fmaxf(fmaxf(fabsf(bq.x), fabsf(bq.y)), fmaxf(fabsf(bq.z), fabsf(bq.w))));
#pragma unroll
  for (int off = 32; off; off >>= 1) m = fmaxf(m, __shfl_xor(m, off));
  if ((threadIdx.x & 63) == 0) wm[threadIdx.x >> 6] = m;
  __syncthreads();
  m = fmaxf(fmaxf(wm[0], wm[1]), fmaxf(wm[2], wm[3]));
  float scale = fmaxf(m * (1.f / 127.f), 1e-8f);
  float invs = 1.f / scale;
  if (isWo) {
    unsigned lo = (unsigned)(q8(a.x, invs) & 255) | ((unsigned)(q8(a.y, invs) & 255) << 8) |
                  ((unsigned)(q8(a.z, invs) & 255) << 16) | ((unsigned)(q8(a.w, invs) & 255) << 24);
    unsigned hi = (unsigned)(q8(bq.x, invs) & 255) | ((unsigned)(q8(bq.y, invs) & 255) << 8) |
                  ((unsigned)(q8(bq.z, invs) & 255) << 16) | ((unsigned)(q8(bq.w, invs) & 255) << 24);
    uint2 pk; pk.x = lo; pk.y = hi;
    ((uint2*)(wo_i8 + (size_t)wx * E_DIM))[threadIdx.x] = pk;
    if (threadIdx.x == 0) wsc[wx] = scale;
  } else {
    unsigned short* orow = wq_all + (size_t)wy * E_DIM * E_DIM + (size_t)wx * E_DIM;
    ushort4 r0, r1;
    r0.x = f2h(fq1(a.x, invs, scale)); r0.y = f2h(fq1(a.y, invs, scale));
    r0.z = f2h(fq1(a.z, invs, scale)); r0.w = f2h(fq1(a.w, invs, scale));
    r1.x = f2h(fq1(bq.x, invs, scale)); r1.y = f2h(fq1(bq.y, invs, scale));
    r1.z = f2h(fq1(bq.z, invs, scale)); r1.w = f2h(fq1(bq.w, invs, scale));
    ((ushort4*)orow)[threadIdx.x * 2] = r0;
    ((ushort4*)orow)[threadIdx.x * 2 + 1] = r1;
  }
}

// ========= 256x192 8-phase double-buffered f16 GEMM (N-fused QKV), XCD-swizzled =====
// N_total = 3*2048 = 6144 fused; grid = 8 (M) x 32 (N) = 256 blocks (ALL CUs).
// 512 threads = 8 waves (2M x 4N), wave-tile 128x48, BK=64 (2 K-steps/tile).
// LDS 112 KiB: buf(56KB) = [A s0 16K][A s1 16K][B s0 12K][B s1 12K], row 64B,
// chunk swizzle cc ^= (row>>1)&3 applied on global src (linear LDS dest).
// Staging of tile t+1 spread over ph1(A s0), ph2(B s0), ph3(A s1), ph4(B s1);
// counted vmcnt(3) at ph2/ph4 end (never drained in-loop).
// LOCALITY SWIZZLE (the R3 fix): each XCD owns iby in [4*xcd, 4*xcd+4) x all
// ibx -> per-XCD B working set = 4 x 768KB = 3MB, L2-resident (R2's mapping
// streamed ALL 24MB of B through each XCD's 4MB L2 -> 102MB HBM fetch,
// latency-bound). A panels (1MB) shared by 4 adjacent blocks; re-reads hit L3.
__global__ __launch_bounds__(512, 2)
void k_gemm_qkv(const unsigned short* __restrict__ A, const unsigned short* __restrict__ Bt,
                unsigned short* __restrict__ C, unsigned* __restrict__ amax, float alpha_q) {
  __shared__ char lds[114688];
  const int K = 2048, NT = 32;
  const int lin = blockIdx.x;
  const int xcd = lin & 7;
  const int i5 = lin >> 3;           // [0,32)
  const int iby = xcd * 4 + (i5 & 3);
  const int ibx = i5 >> 2;           // [0,8)

  const int tid = threadIdx.x;
  const int wv = tid >> 6, ln = tid & 63;
  const int wm = wv >> 2, wn = wv & 3;
  const size_t bm = (size_t)ibx * 256, bn = (size_t)iby * 192;
  const int arow = ln & 15, gsl = ln >> 4;

  // LDS read byte offsets within one 56KB buffer (A k-step: +16384; B: +12288)
  int abyte[8], bbyte[3];
#pragma unroll
  for (int i = 0; i < 8; ++i) {
    int r = wm * 128 + i * 16 + arow;
    abyte[i] = r * 64 + ((gsl ^ ((r >> 1) & 3)) * 16);
  }
#pragma unroll
  for (int j = 0; j < 3; ++j) {
    int r = wn * 48 + j * 16 + arow;
    bbyte[j] = 32768 + r * 64 + ((gsl ^ ((r >> 1) & 3)) * 16);
  }

  // staging: thread tid covers row (tid>>2) [+128] of a 256(192)x32 chunk;
  // pre-swizzled global source col-chunk so linear LDS dest + swizzled read agree
  const int srow = tid >> 2;
  const int scc = (tid & 3) ^ ((tid >> 3) & 3);
  const unsigned short* Asrc = A + (bm + srow) * (size_t)K + scc * 8;
  const unsigned short* Bsrc = Bt + (bn + srow) * (size_t)K + scc * 8;
  const int ldst = tid * 16;

#define BUFOF(T) (((T) & 1) * 57344)
#define STGA(T, S) do { \
    char* d_ = lds + BUFOF(T) + (S) * 16384 + ldst; \
    const unsigned short* s_ = Asrc + (T) * 64 + (S) * 32; \
    gload_lds16(s_, d_); \
    gload_lds16(s_ + (size_t)128 * K, d_ + 8192); } while (0)
#define STGB(T, S) do { \
    char* d_ = lds + BUFOF(T) + 32768 + (S) * 12288 + ldst; \
    const unsigned short* s_ = Bsrc + (T) * 64 + (S) * 32; \
    gload_lds16(s_, d_); \
    if (tid < 256) gload_lds16(s_ + (size_t)128 * K, d_ + 8192); } while (0)

  f32x4 acc[8][3];
#pragma unroll
  for (int i = 0; i < 8; ++i)
#pragma unroll
    for (int j = 0; j < 3; ++j) { acc[i][j][0] = 0.f; acc[i][j][1] = 0.f; acc[i][j][2] = 0.f; acc[i][j][3] = 0.f; }

  // prologue: stage all of tile 0, drain (prologue only), barrier
  STGA(0, 0); STGB(0, 0); STGA(0, 1); STGB(0, 1);
  VMW0();
  BARR();

  // One K-tile = 4 phases x 12 MFMA.
#define TILE(BUF, DS, T1, W2X, W4X) do { \
    char* bp_ = lds + (BUF); \
    short8 af_[4], bf_[3], ag_[4]; \
    /* ---- phase 1: i0..3 x j0..2, k-step 0; stage A(t+1) s0 ---- */ \
    _Pragma("unroll") for (int i = 0; i < 4; ++i) af_[i] = *(const short8*)(bp_ + abyte[i]); \
    _Pragma("unroll") for (int j = 0; j < 3; ++j) bf_[j] = *(const short8*)(bp_ + bbyte[j]); \
    if (DS) STGA(T1, 0); \
    BARR(); LGKM0(); \
    __builtin_amdgcn_s_setprio(1); \
    _Pragma("unroll") for (int i = 0; i < 4; ++i) \
      _Pragma("unroll") for (int j = 0; j < 3; ++j) acc[i][j] = mfma16h(af_[i], bf_[j], acc[i][j]); \
    __builtin_amdgcn_s_setprio(0); \
    BARR(); \
    /* ---- phase 2: i4..7 x j0..2, k-step 0; stage B(t+1) s0 ---- */ \
    _Pragma("unroll") for (int i = 0; i < 4; ++i) ag_[i] = *(const short8*)(bp_ + abyte[4 + i]); \
    if (DS) STGB(T1, 0); \
    BARR(); LGKM0(); \
    __builtin_amdgcn_s_setprio(1); \
    _Pragma("unroll") for (int i = 0; i < 4; ++i) \
      _Pragma("unroll") for (int j = 0; j < 3; ++j) acc[4 + i][j] = mfma16h(ag_[i], bf_[j], acc[4 + i][j]); \
    __builtin_amdgcn_s_setprio(0); \
    W2X; \
    BARR(); \
    /* ---- phase 3: i0..3 x j0..2, k-step 1; stage A(t+1) s1 ---- */ \
    _Pragma("unroll") for (int i = 0; i < 4; ++i) af_[i] = *(const short8*)(bp_ + 16384 + abyte[i]); \
    _Pragma("unroll") for (int j = 0; j < 3; ++j) bf_[j] = *(const short8*)(bp_ + 12288 + bbyte[j]); \
    if (DS) STGA(T1, 1); \
    BARR(); LGKM0(); \
    __builtin_amdgcn_s_setprio(1); \
    _Pragma("unroll") for (int i = 0; i < 4; ++i) \
      _Pragma("unroll") for (int j = 0; j < 3; ++j) acc[i][j] = mfma16h(af_[i], bf_[j], acc[i][j]); \
    __builtin_amdgcn_s_setprio(0); \
    BARR(); \
    /* ---- phase 4: i4..7 x j0..2, k-step 1; stage B(t+1) s1 ---- */ \
    _Pragma("unroll") for (int i = 0; i < 4; ++i) ag_[i] = *(const short8*)(bp_ + 16384 + abyte[4 + i]); \
    if (DS) STGB(T1, 1); \
    BARR(); LGKM0(); \
    __builtin_amdgcn_s_setprio(1); \
    _Pragma("unroll") for (int i = 0; i < 4; ++i) \
      _Pragma("unroll") for (int j = 0; j < 3; ++j) acc[4 + i][j] = mfma16h(ag_[i], bf_[j], acc[4 + i][j]); \
    __builtin_amdgcn_s_setprio(0); \
    W4X; \
    BARR(); \
  } while (0)

#pragma unroll 1
  for (int t = 0; t < NT - 2; t += 2) {
    TILE(0, 1, t + 1, VMW3(), VMW3());
    TILE(57344, 1, t + 2, VMW3(), VMW3());
  }
  TILE(0, 1, NT - 1, VMW3(), VMW3());
  TILE(57344, 0, 0, VMW0(), (void)0);
#undef TILE
#undef STGA
#undef STGB
#undef BUFOF

  // epilogue: per-j z (16-col fragments never straddle the 2048 boundary)
#pragma unroll
  for (int j = 0; j < 3; ++j) {
    const int colbase = (int)bn + wn * 48 + j * 16;  // wave-uniform
    const int zj = colbase >> 11;
    const float alpha = (zj == 0) ? alpha_q : 1.0f;
    unsigned short* Cz = C + (size_t)zj * S_LEN * E_DIM;
    const int col = (colbase & 2047) + arow;
    float amxj = 0.f;
#pragma unroll
    for (int i = 0; i < 8; ++i) {
      size_t rowb = bm + wm * 128 + i * 16 + gsl * 4;
#pragma unroll
      for (int r = 0; r < 4; ++r) {
        float v = acc[i][j][r] * alpha;
        Cz[(rowb + r) * E_DIM + col] = f2h(v);
        amxj = fmaxf(amxj, fabsf(v));
      }
    }
#pragma unroll
    for (int off = 32; off; off >>= 1) amxj = fmaxf(amxj, __shfl_xor(amxj, off));
    if (ln == 0) atomicMax(amax + zj, __float_as_uint(amxj));
  }
}

// ========= o-proj: 128x64 tri-buffered INT8 GEMM, XCD-swizzled =========
__global__ __launch_bounds__(256, 4)
void k_gemm_o(const signed char* __restrict__ A, const signed char* __restrict__ Bt,
              float* __restrict__ C, const unsigned* __restrict__ sc,
              const float* __restrict__ wsc) {
  __shared__ char lds[36864];
  const int K = 2048, NT = 32;
  const float sa = fmaxf(__uint_as_float(sc[3]) * (1.f / 127.f), 1e-8f);
  const int lin = blockIdx.y * 16 + blockIdx.x;
  const int swz = (lin & 7) * 64 + (lin >> 3);
  const int iby = swz >> 4;
  const int ibx = swz & 15;

  const int tid = threadIdx.x;
  const int wv = tid >> 6, ln = tid & 63;
  const int wm = wv >> 1, wn = wv & 1;
  const size_t bm = (size_t)ibx * 128, bn = (size_t)iby * 64;
  const int arow = ln & 15, gsl = ln >> 4;

  int abyte[4], bbyte[2];
#pragma unroll
  for (int i = 0; i < 4; ++i) {
    int ra = wm * 64 + i * 16 + arow;
    abyte[i] = ra * 64 + ((gsl ^ ((ra >> 1) & 3)) * 16);
  }
#pragma unroll
  for (int j = 0; j < 2; ++j) {
    int rb = wn * 32 + j * 16 + arow;
    bbyte[j] = rb * 64 + ((gsl ^ ((rb >> 1) & 3)) * 16);
  }

  const int srow = tid >> 2;
  const int sl = (tid & 3) ^ ((srow >> 1) & 3);
  const signed char* Ast = A + (bm + srow) * (size_t)K + sl * 16;
  const signed char* Bst = Bt + (bn + srow) * (size_t)K + sl * 16;

#define STG(T, dst) do { if ((T) < NT) { \
    size_t go = (size_t)(T) * 64; \
    gload_lds16(Ast + go, (dst) + wv * 1024); \
    gload_lds16(Ast + go + (size_t)64 * K, (dst) + 4096 + wv * 1024); \
    gload_lds16(Bst + go, (dst) + 8192 + wv * 1024); } } while (0)

  i32x4 acc[4][2];
#pragma unroll
  for (int i = 0; i < 4; ++i)
#pragma unroll
    for (int j = 0; j < 2; ++j) { acc[i][j][0] = 0; acc[i][j][1] = 0; acc[i][j][2] = 0; acc[i][j][3] = 0; }

  char* b0 = lds;
  char* b1 = lds + 12288;
  char* b2 = lds + 24576;

  STG(0, b0); STG(1, b1);
  VMW3();
  BARR();

#define ITER(T, bufR, bufS) do { \
    i32x4 af[4], bf[2]; \
    _Pragma("unroll") \
    for (int i = 0; i < 4; ++i) af[i] = *(const i32x4*)((bufR) + abyte[i]); \
    _Pragma("unroll") \
    for (int j = 0; j < 2; ++j) bf[j] = *(const i32x4*)((bufR) + 8192 + bbyte[j]); \
    STG((T) + 2, bufS); \
    __builtin_amdgcn_s_setprio(1); \
    _Pragma("unroll") \
    for (int i = 0; i < 4; ++i) \
      _Pragma("unroll") \
      for (int j = 0; j < 2; ++j) acc[i][j] = mfma16i8(af[i], bf[j], acc[i][j]); \
    __builtin_amdgcn_s_setprio(0); \
    if ((T) == NT - 2) { VMW0(); } else if ((T) < NT - 2) { VMW3(); } \
    BARR(); } while (0)

#pragma unroll 1
  for (int t = 0; t + 2 < NT; t += 3) {
    ITER(t, b0, b2);
    ITER(t + 1, b1, b0);
    ITER(t + 2, b2, b1);
  }
  ITER(NT - 2, b0, b2);
  ITER(NT - 1, b1, b0);
#undef ITER
#undef STG

#pragma unroll
  for (int i = 0; i < 4; ++i) {
    size_t rowb = bm + wm * 64 + i * 16 + gsl * 4;
#pragma unroll
    for (int j = 0; j < 2; ++j) {
      size_t col = bn + wn * 32 + j * 16 + arow;
      float s = sa * wsc[col];
#pragma unroll
      for (int r = 0; r < 4; ++r)
        C[(rowb + r) * E_DIM + col] = (float)acc[i][j][r] * s;
    }
  }
}

// ========= merged RoPE(q,k, table-driven) + V-transpose (f16 in/out) =========
__global__ void k_rvt(const unsigned short* __restrict__ qkv,
                      unsigned short* __restrict__ Qh, unsigned short* __restrict__ Kh,
                      unsigned short* __restrict__ Vt, const unsigned* __restrict__ sc,
                      const float2* __restrict__ trig) {
  __shared__ float tb[64][65];
  const int z = blockIdx.z;
  if (z < 2) {
    const unsigned short* x = qkv + (z ? 4194304 : 0);
    unsigned short* out = z ? Kh : Qh;
    float scale = fmaxf(__uint_as_float(sc[z]) * (1.f / 127.f), 1e-8f);
    float invs = 1.f / scale;
    int h = blockIdx.y;
    int s = blockIdx.x * 8 + (threadIdx.x >> 5);
    int i = threadIdx.x & 31;
    size_t base = (size_t)s * E_DIM + h * 64 + i;
    float x0 = h2f(x[base]);
    float x1 = h2f(x[base + 32]);
    float q0 = fq1(x0, invs, scale);
    float q1 = fq1(x1, invs, scale);
    float2 t = trig[s * 32 + i];
    size_t ob = (size_t)h * S_LEN * D_DIM + (size_t)s * D_DIM + i;
    out[ob] = f2h(q0 * t.x - q1 * t.y);
    out[ob + 32] = f2h(q1 * t.x + q0 * t.y);
    return;
  }
  if (blockIdx.x >= 32) return;
  const unsigned short* v = qkv + 2 * 4194304;
  float scale = fmaxf(__uint_as_float(sc[2]) * (1.f / 127.f), 1e-8f);
  float invs = 1.f / scale;
  int s0 = blockIdx.x * 64, h = blockIdx.y;
#pragma unroll
  for (int l = 0; l < 16; ++l) {
    int idx = threadIdx.x + l * 256;
    int r = idx >> 6, c = idx & 63;
    float x = h2f(v[(size_t)(s0 + r) * E_DIM + h * 64 + c]);
    tb[r][c] = fq1(x, invs, scale);
  }
  __syncthreads();
#pragma unroll
  for (int l = 0; l < 16; ++l) {
    int idx = threadIdx.x + l * 256;
    int d = idx >> 6, s = idx & 63;
    Vt[(size_t)h * D_DIM * S_LEN + (size_t)d * S_LEN + s0 + s] = f2h(tb[s][d]);
  }
}

// -------- causal flash attention: 40KB LDS -> 4 blocks/CU (16 waves/CU) --------
__global__ __launch_bounds__(256, 4)
void k_attn(const unsigned short* __restrict__ Qh, const unsigned short* __restrict__ Kh,
            const unsigned short* __restrict__ Vt, unsigned short* __restrict__ att,
            unsigned* __restrict__ amax) {
  __shared__ char Kbuf[2 * 8192];
  __shared__ char Vbuf[2 * 8192];
  __shared__ __align__(16) char Pb[8192];
  const int L = blockIdx.x;
  const int h = L & 31;
  const int qc = 31 - (L >> 5);
  const int nt = qc + 1;
  const int tid = threadIdx.x;
  const int wv = tid >> 6, ln = tid & 63;
  const int arow = ln & 15, gsl = ln >> 4;
  const unsigned short* Qb = Qh + (size_t)h * S_LEN * D_DIM;
  const unsigned short* Kb = Kh + (size_t)h * S_LEN * D_DIM;
  const unsigned short* Vb = Vt + (size_t)h * D_DIM * S_LEN;
  const int qr = qc * 64 + wv * 16;

  const int srow0 = tid >> 3, sch0 = (tid & 7) ^ (srow0 & 7);
  const int srow1 = 32 + (tid >> 3), sch1 = (tid & 7) ^ (srow1 & 7);

#define STAGEK(T, B) do { char* kd = Kbuf + (B) * 8192; const int tb_ = (T) * 64; \
    gload_lds16(Kb + (size_t)(tb_ + srow0) * D_DIM + sch0 * 8, kd + wv * 1024); \
    gload_lds16(Kb + (size_t)(tb_ + srow1) * D_DIM + sch1 * 8, kd + 4096 + wv * 1024); } while (0)
#define STAGEV(T, B) do { char* vd = Vbuf + (B) * 8192; const int tb_ = (T) * 64; \
    gload_lds16(Vb + (size_t)srow0 * S_LEN + tb_ + sch0 * 8, vd + wv * 1024); \
    gload_lds16(Vb + (size_t)srow1 * S_LEN + tb_ + sch1 * 8, vd + 4096 + wv * 1024); } while (0)

  short8 qa0 = *(const short8*)(Qb + (size_t)(qr + arow) * D_DIM + gsl * 8);
  short8 qa1 = *(const short8*)(Qb + (size_t)(qr + arow) * D_DIM + 32 + gsl * 8);

  f32x4 o[4];
  float mrow = -INFINITY, lrow = 0.f;
#pragma unroll
  for (int d = 0; d < 4; ++d) { o[d][0] = 0.f; o[d][1] = 0.f; o[d][2] = 0.f; o[d][3] = 0.f; }

  STAGEK(0, 0);
  STAGEV(0, 0);
  if (nt > 1) { STAGEK(1, 1); STAGEV(1, 1); VMW4(); } else { VMW0(); }
  BARR();

  char* Pw = Pb + wv * 2048 + arow * 128;
  const int arw7 = arow & 7;

#pragma unroll 1
  for (int t = 0; t < nt; ++t) {
    if (t >= 1 && t + 1 < nt) { STAGEK(t + 1, (t + 1) & 1); STAGEV(t + 1, (t + 1) & 1); }
    char* kb = Kbuf + (t & 1) * 8192;
    char* vb = Vbuf + (t & 1) * 8192;

    short8 kf[4][2];
#pragma unroll
    for (int kvb = 0; kvb < 4; ++kvb) {
      int row = kvb * 16 + arow;
      int sw = (row & 7) << 4;
      kf[kvb][0] = *(const short8*)(kb + row * 128 + ((gsl * 16) ^ sw));
      kf[kvb][1] = *(const short8*)(kb + row * 128 + ((64 + gsl * 16) ^ sw));
    }
    f32x4 s4[4];
#pragma unroll
    for (int kvb = 0; kvb < 4; ++kvb) {
      s4[kvb][0] = 0.f; s4[kvb][1] = 0.f; s4[kvb][2] = 0.f; s4[kvb][3] = 0.f;
    }
#pragma unroll
    for (int kvb = 0; kvb < 4; ++kvb) {
      s4[kvb] = mfma16h(kf[kvb][0], qa0, s4[kvb]);
      s4[kvb] = mfma16h(kf[kvb][1], qa1, s4[kvb]);
    }

    const int t0 = t * 64;
    const int qrow = qr + arow;
    if (t0 + 63 > qrow) {
#pragma unroll
      for (int kvb = 0; kvb < 4; ++kvb) {
        int colb = t0 + kvb * 16 + gsl * 4;
#pragma unroll
        for (int r = 0; r < 4; ++r)
          if (colb + r > qrow) s4[kvb][r] = -INFINITY;
      }
    }

    float smax = s4[0][0];
#pragma unroll
    for (int kvb = 0; kvb < 4; ++kvb)
#pragma unroll
      for (int r = 0; r < 4; ++r) smax = fmaxf(smax, s4[kvb][r]);
    smax = fmaxf(smax, __shfl_xor(smax, 16));
    smax = fmaxf(smax, __shfl_xor(smax, 32));

    float mn = fmaxf(mrow, smax);
    float corr = __expf(mrow - mn);
    mrow = mn;

    float rs = 0.f;
    float p[4][4];
#pragma unroll
    for (int kvb = 0; kvb < 4; ++kvb)
#pragma unroll
      for (int r = 0; r < 4; ++r) {
        p[kvb][r] = __expf(s4[kvb][r] - mn);
        rs += p[kvb][r];
      }
    rs += __shfl_xor(rs, 16);
    rs += __shfl_xor(rs, 32);
    lrow = lrow * corr + rs;

    float corr_r[4];
#pragma unroll
    for (int r = 0; r < 4; ++r) corr_r[r] = __shfl(corr, gsl * 4 + r);
#pragma unroll
    for (int d = 0; d < 4; ++d)
#pragma unroll
      for (int r = 0; r < 4; ++r) o[d][r] *= corr_r[r];

    __builtin_amdgcn_wave_barrier();
#pragma unroll
    for (int kvb = 0; kvb < 4; ++kvb) {
      short4v pw;
      pw[0] = (short)f2h(p[kvb][0]);
      pw[1] = (short)f2h(p[kvb][1]);
      pw[2] = (short)f2h(p[kvb][2]);
      pw[3] = (short)f2h(p[kvb][3]);
      const int u = kvb * 2 + (gsl >> 1);
      *(short4v*)(Pw + ((u ^ arw7) << 4) + ((gsl & 1) << 3)) = pw;
    }
    __builtin_amdgcn_wave_barrier();
    short8 pa0 = *(const short8*)(Pw + ((gsl ^ arw7) << 4));
    short8 pa1 = *(const short8*)(Pw + (((4 + gsl) ^ arw7) << 4));
    __builtin_amdgcn_wave_barrier();

    short8 vf[4][2];
#pragma unroll
    for (int d = 0; d < 4; ++d) {
      int row = d * 16 + arow;
      int sw = (row & 7) << 4;
      vf[d][0] = *(const short8*)(vb + row * 128 + ((gsl * 16) ^ sw));
      vf[d][1] = *(const short8*)(vb + row * 128 + ((64 + gsl * 16) ^ sw));
    }
#pragma unroll
    for (int d = 0; d < 4; ++d) {
      o[d] = mfma16h(pa0, vf[d][0], o[d]);
      o[d] = mfma16h(pa1, vf[d][1], o[d]);
    }

    VMW0();
    BARR();
  }
#undef STAGEK
#undef STAGEV

  float amx = 0.f;
  float invl = 1.f / lrow;
  float invl_r[4];
#pragma unroll
  for (int r = 0; r < 4; ++r) invl_r[r] = __shfl(invl, gsl * 4 + r);
#pragma unroll
  for (int r = 0; r < 4; ++r) {
    size_t row = (size_t)(qr + gsl * 4 + r);
#pragma unroll
    for (int d = 0; d < 4; ++d) {
      float v = o[d][r] * invl_r[r];
      att[row * E_DIM + h * 64 + d * 16 + arow] = f2h(v);
      amx = fmaxf(amx, fabsf(v));
    }
  }

#pragma unroll
  for (int off = 32; off; off >>= 1) amx = fmaxf(amx, __shfl_xor(amx, off));
  if (ln == 0) atomicMax(amax + 3, __float_as_uint(amx));
}

// ---------------- act fake-quant f16 -> packed int8 (8 elems/thread) ----------------
__global__ void k_quant_act_i8(const unsigned short* __restrict__ in, uint2* __restrict__ out,
                               const unsigned* __restrict__ sc, int idx) {
  float scale = fmaxf(__uint_as_float(sc[idx]) * (1.f / 127.f), 1e-8f);
  float invs = 1.f / scale;
  int i = blockIdx.x * blockDim.x + threadIdx.x;
  short8 v = ((const short8*)in)[i];
  unsigned lo = 0, hi = 0;
#pragma unroll
  for (int e = 0; e < 4; ++e)
    lo |= (unsigned)(q8(h2f((unsigned short)v[e]), invs) & 255) << (8 * e);
#pragma unroll
  for (int e = 0; e < 4; ++e)
    hi |= (unsigned)(q8(h2f((unsigned short)v[4 + e]), invs) & 255) << (8 * e);
  uint2 pk; pk.x = lo; pk.y = hi;
  out[i] = pk;
}

extern "C" void kernel_launch(void* const* d_in, const int* in_sizes, int n_in,
                              void* d_out, int out_size, void* d_ws, size_t ws_size,
                              hipStream_t stream) {
  const float* hs = (const float*)d_in[0];
  const float* w_q = (const float*)d_in[1];
  const float* w_k = (const float*)d_in[2];
  const float* w_v = (const float*)d_in[3];
  const float* w_o = (const float*)d_in[4];

  char* ws = (char*)d_ws;
  unsigned short* wq_all = (unsigned short*)(ws);                 // 3 x E*E f16 (q,k,v)
  signed char* wo_i8 = (signed char*)(ws + 25165824);             // E*E i8
  float* wsc = (float*)(ws + 29360128);                           // 2048 f32
  float2* trig = (float2*)(ws + 30408704);                        // 65536 float2 (512KB)
  unsigned short* hsb = (unsigned short*)(ws + 33554432);         // S*E f16
  unsigned short* qkv16 = (unsigned short*)(ws + 41943040);       // 3 x S*E f16
  unsigned short* att = qkv16;                                    // alias q slab (f16)
  signed char* aq_i8 = (signed char*)(ws + 67108864);             // S*E i8
  unsigned short* Qh = (unsigned short*)(ws + 92274688);          // [H][S][D] f16
  unsigned short* Kh = (unsigned short*)(ws + 100663296);
  unsigned short* Vt = (unsigned short*)(ws + 109051904);         // [H][D][S] f16
  unsigned* sc = (unsigned*)(ws + 117440512);                     // absmax scalars

  k_prep<<<12545, 256, 0, stream>>>(hs, w_q, w_k, w_v, w_o, hsb, wq_all, wo_i8, wsc, sc, trig);
  k_gemm_qkv<<<dim3(256), 512, 0, stream>>>(hsb, wq_all, qkv16, sc, 0.125f);
  k_rvt<<<dim3(256, 32, 3), 256, 0, stream>>>(qkv16, Qh, Kh, Vt, sc, trig);
  k_attn<<<1024, 256, 0, stream>>>(Qh, Kh, Vt, att, sc);
  k_quant_act_i8<<<2048, 256, 0, stream>>>(att, (uint2*)aq_i8, sc, 3);
  k_gemm_o<<<dim3(16, 32), 256, 0, stream>>>(aq_i8, wo_i8, (float*)d_out, sc, wsc);
}

// Round 5
// 237.508 us; speedup vs baseline: 1.0114x; 1.0048x over previous
//
#include <hip/hip_runtime.h>
#include <hip/hip_bf16.h>
#include <hip/hip_fp16.h>

#define S_LEN 2048
#define E_DIM 2048
#define H_NUM 32
#define D_DIM 64

typedef __attribute__((ext_vector_type(8))) short short8;
typedef __attribute__((ext_vector_type(4))) short short4v;
typedef __attribute__((ext_vector_type(4))) float f32x4;
typedef __attribute__((ext_vector_type(4))) int i32x4;

__device__ __forceinline__ unsigned short f2h(float f) {
  return __builtin_bit_cast(unsigned short, (_Float16)f);
}

__device__ __forceinline__ float h2f(unsigned short u) {
  return (float)__builtin_bit_cast(_Float16, u);
}

__device__ __forceinline__ float fq1(float x, float invs, float scale) {
  return fminf(fmaxf(rintf(x * invs), -128.f), 127.f) * scale;
}

__device__ __forceinline__ int q8(float x, float invs) {
  return min(max((int)rintf(x * invs), -128), 127);
}

__device__ __forceinline__ void gload_lds16(const void* g, void* l) {
  __builtin_amdgcn_global_load_lds((const __attribute__((address_space(1))) void*)g,
                                   (__attribute__((address_space(3))) void*)l, 16, 0, 0);
}

__device__ __forceinline__ f32x4 mfma16h(short8 a, short8 b, f32x4 c) {
  return __builtin_amdgcn_mfma_f32_16x16x32_f16(a, b, c, 0, 0, 0);
}

__device__ __forceinline__ i32x4 mfma16i8(i32x4 a, i32x4 b, i32x4 c) {
  return __builtin_amdgcn_mfma_i32_16x16x64_i8(a, b, c, 0, 0, 0);
}

#define VMW4() asm volatile("s_waitcnt vmcnt(4)" ::: "memory")
#define VMW3() asm volatile("s_waitcnt vmcnt(3)" ::: "memory")
#define VMW0() asm volatile("s_waitcnt vmcnt(0)" ::: "memory")
#define BARR() asm volatile("s_barrier" ::: "memory")
#define LGKM0() asm volatile("s_waitcnt lgkmcnt(0)" ::: "memory")

// ========= merged prologue: cvt + quant_w + quant_wo + sc init + RoPE table =========
// blocks [0,4096): hs cvt; [4096,10240): w_{q,k,v}; [10240,12288): w_o->i8;
// b==12288: sc init; [12289,12545): cos/sin table (65536 (s,i) pairs, f32x2).
__global__ void k_prep(const float* __restrict__ hs,
                       const float* __restrict__ w_q, const float* __restrict__ w_k,
                       const float* __restrict__ w_v, const float* __restrict__ w_o,
                       unsigned short* __restrict__ hsb, unsigned short* __restrict__ wq_all,
                       signed char* __restrict__ wo_i8, float* __restrict__ wsc,
                       unsigned* __restrict__ sc, float2* __restrict__ trig) {
  const int b = blockIdx.x;
  if (b < 4096) {
    int i = b * 256 + threadIdx.x;
    float4 v = ((const float4*)hs)[i];
    ushort4 r;
    r.x = f2h(v.x); r.y = f2h(v.y); r.z = f2h(v.z); r.w = f2h(v.w);
    ((ushort4*)hsb)[i] = r;
    return;
  }
  if (b >= 12288) {
    if (b == 12288) {
      if (threadIdx.x < 8) sc[threadIdx.x] = 0u;
      return;
    }
    // trig table: idx = (b-12289)*256 + tid -> s = idx>>5, i = idx&31
    int idx = (b - 12289) * 256 + threadIdx.x;
    int s = idx >> 5, i = idx & 31;
    float freq = exp2f(-(float)i * (13.287712379549449f / 32.f));
    float ang = (float)s * freq;
    float sn, cs;
    sincosf(ang, &sn, &cs);
    float2 t; t.x = cs; t.y = sn;
    trig[idx] = t;
    return;
  }
  __shared__ float wm[4];
  const int isWo = (b >= 10240);
  const int bb = isWo ? (b - 10240) : (b - 4096);
  const int wy = isWo ? 0 : (bb >> 11);
  const int wx = isWo ? bb : (bb & 2047);
  const float* w = isWo ? w_o : (wy == 0 ? w_q : wy == 1 ? w_k : w_v);
  const float* row = w + (size_t)wx * E_DIM;
  float4 a = ((const float4*)row)[threadIdx.x * 2];
  float4 bq = ((const float4*)row)[threadIdx.x * 2 + 1];
  float m = fmaxf(fmaxf(fmaxf(fabsf(a.x), fabsf(a.y)), fmaxf(fabsf(a.z), fabsf(a.w))),
                  fmaxf(fmaxf(fabsf(bq.x), fabsf(bq.y)), fmaxf(fabsf(bq.z), fabsf(bq.w))));
#pragma unroll
  for (int off = 32; off; off >>= 1) m = fmaxf(m, __shfl_xor(m, off));
  if ((threadIdx.x & 63) == 0) wm[threadIdx.x >> 6] = m;
  __syncthreads();
  m = fmaxf(fmaxf(wm[0], wm[1]), fmaxf(wm[2], wm[3]));
  float scale = fmaxf(m * (1.f / 127.f), 1e-8f);
  float invs = 1.f / scale;
  if (isWo) {
    unsigned lo = (unsigned)(q8(a.x, invs) & 255) | ((unsigned)(q8(a.y, invs) & 255) << 8) |
                  ((unsigned)(q8(a.z, invs) & 255) << 16) | ((unsigned)(q8(a.w, invs) & 255) << 24);
    unsigned hi = (unsigned)(q8(bq.x, invs) & 255) | ((unsigned)(q8(bq.y, invs) & 255) << 8) |
                  ((unsigned)(q8(bq.z, invs) & 255) << 16) | ((unsigned)(q8(bq.w, invs) & 255) << 24);
    uint2 pk; pk.x = lo; pk.y = hi;
    ((uint2*)(wo_i8 + (size_t)wx * E_DIM))[threadIdx.x] = pk;
    if (threadIdx.x == 0) wsc[wx] = scale;
  } else {
    unsigned short* orow = wq_all + (size_t)wy * E_DIM * E_DIM + (size_t)wx * E_DIM;
    ushort4 r0, r1;
    r0.x = f2h(fq1(a.x, invs, scale)); r0.y = f2h(fq1(a.y, invs, scale));
    r0.z = f2h(fq1(a.z, invs, scale)); r0.w = f2h(fq1(a.w, invs, scale));
    r1.x = f2h(fq1(bq.x, invs, scale)); r1.y = f2h(fq1(bq.y, invs, scale));
    r1.z = f2h(fq1(bq.z, invs, scale)); r1.w = f2h(fq1(bq.w, invs, scale));
    ((ushort4*)orow)[threadIdx.x * 2] = r0;
    ((ushort4*)orow)[threadIdx.x * 2 + 1] = r1;
  }
}

// ========= 256x192 8-phase double-buffered f16 GEMM (N-fused QKV), XCD-swizzled =====
// Grid = 256 blocks (all CUs), 512 threads = 8 waves (2M x 4N), BK=64.
// LDS 112 KiB: buf(56KB) = [A s0 16K][A s1 16K][B 24K contiguous (s0 12K|s1 12K)].
// R4 FIX: staging is WAVE-UNIFORM (7 loads/thread/tile, identical all waves):
//   ph1: A-s0 (2 rounds), ph2: B rounds 0+1 (2), ph3: A-s1 (2), ph4: B round 2 (1).
//   B rounds are 8KB slices of the contiguous 24KB region (round 1 straddles the
//   s0/s1 boundary: addresses diverge across waves, COUNTS don't).
// Waits: W2X=vmcnt(4) drains the 3 leftovers {A-s1, B2} staged >=2 phases ago
// (guards ph3/4); W4X=vmcnt(3) drains ph1+ph2's 4 (guards next tile's ph1).
// No wait ever touches a load younger than 2 phases (R2/R3's divergent STGB made
// waves 0-3 drain CURRENT-phase loads at every W2X/W4X -> +3.3k cy/tile stall).
__global__ __launch_bounds__(512, 2)
void k_gemm_qkv(const unsigned short* __restrict__ A, const unsigned short* __restrict__ Bt,
                unsigned short* __restrict__ C, unsigned* __restrict__ amax, float alpha_q) {
  __shared__ char lds[114688];
  const int K = 2048, NT = 32;
  // locality swizzle (R3, keeps FETCH at 45MB): each XCD owns 4 iby x all ibx
  const int lin = blockIdx.x;
  const int xcd = lin & 7;
  const int i5 = lin >> 3;           // [0,32)
  const int iby = xcd * 4 + (i5 & 3);
  const int ibx = i5 >> 2;           // [0,8)

  const int tid = threadIdx.x;
  const int wv = tid >> 6, ln = tid & 63;
  const int wm = wv >> 2, wn = wv & 3;
  const size_t bm = (size_t)ibx * 256, bn = (size_t)iby * 192;
  const int arow = ln & 15, gsl = ln >> 4;

  // LDS read byte offsets within one 56KB buffer (A k-step: +16384; B k-step: +12288)
  int abyte[8], bbyte[3];
#pragma unroll
  for (int i = 0; i < 8; ++i) {
    int r = wm * 128 + i * 16 + arow;
    abyte[i] = r * 64 + ((gsl ^ ((r >> 1) & 3)) * 16);
  }
#pragma unroll
  for (int j = 0; j < 3; ++j) {
    int r = wn * 48 + j * 16 + arow;
    bbyte[j] = 32768 + r * 64 + ((gsl ^ ((r >> 1) & 3)) * 16);
  }

  // A staging (uniform, 2 loads/call): thread tid covers rows (tid>>2), +128 of a
  // 256x32 k-half; pre-swizzled global source chunk so linear LDS dest + swizzled
  // read agree.
  const int srow = tid >> 2;
  const int scc = (tid & 3) ^ ((tid >> 3) & 3);
  const unsigned short* Asrc = A + (bm + srow) * (size_t)K + scc * 8;
  const int ldst = tid * 16;

  // B staging (uniform, 1 load/round): 3 x 8KB rounds over the contiguous 24KB
  // region. Region byte rb = m*8192 + tid*16 -> (s, row, chunk) -> pre-swizzled src.
  const unsigned short* Bsrc_r[3];
#pragma unroll
  for (int m = 0; m < 3; ++m) {
    int rb = m * 8192 + tid * 16;
    int s = (rb >= 12288) ? 1 : 0;
    int within = rb - s * 12288;
    int r = within >> 6;
    int c = (within >> 4) & 3;
    int cs = c ^ ((r >> 1) & 3);
    Bsrc_r[m] = Bt + (bn + (size_t)r) * (size_t)K + s * 32 + cs * 8;
  }

#define BUFOF(T) (((T) & 1) * 57344)
#define STGA(T, S) do { \
    char* d_ = lds + BUFOF(T) + (S) * 16384 + ldst; \
    const unsigned short* s_ = Asrc + (T) * 64 + (S) * 32; \
    gload_lds16(s_, d_); \
    gload_lds16(s_ + (size_t)128 * K, d_ + 8192); } while (0)
#define STGBR(T, M) do { \
    char* d_ = lds + BUFOF(T) + 32768 + (M) * 8192 + ldst; \
    gload_lds16(Bsrc_r[M] + (size_t)(T) * 64, d_); } while (0)

  f32x4 acc[8][3];
#pragma unroll
  for (int i = 0; i < 8; ++i)
#pragma unroll
    for (int j = 0; j < 3; ++j) { acc[i][j][0] = 0.f; acc[i][j][1] = 0.f; acc[i][j][2] = 0.f; acc[i][j][3] = 0.f; }

  // prologue: stage all of tile 0 (7 rounds), drain (prologue only), barrier
  STGA(0, 0); STGA(0, 1); STGBR(0, 0); STGBR(0, 1); STGBR(0, 2);
  VMW0();
  BARR();

  // One K-tile = 4 phases x 12 MFMA.
#define TILE(BUF, DS, T1, W2X, W4X) do { \
    char* bp_ = lds + (BUF); \
    short8 af_[4], bf_[3], ag_[4]; \
    /* ---- phase 1: i0..3 x j0..2, k-step 0; stage A(t+1) s0 (2) ---- */ \
    _Pragma("unroll") for (int i = 0; i < 4; ++i) af_[i] = *(const short8*)(bp_ + abyte[i]); \
    _Pragma("unroll") for (int j = 0; j < 3; ++j) bf_[j] = *(const short8*)(bp_ + bbyte[j]); \
    if (DS) STGA(T1, 0); \
    BARR(); LGKM0(); \
    __builtin_amdgcn_s_setprio(1); \
    _Pragma("unroll") for (int i = 0; i < 4; ++i) \
      _Pragma("unroll") for (int j = 0; j < 3; ++j) acc[i][j] = mfma16h(af_[i], bf_[j], acc[i][j]); \
    __builtin_amdgcn_s_setprio(0); \
    BARR(); \
    /* ---- phase 2: i4..7 x j0..2, k-step 0; stage B(t+1) rounds 0+1 (2) ---- */ \
    _Pragma("unroll") for (int i = 0; i < 4; ++i) ag_[i] = *(const short8*)(bp_ + abyte[4 + i]); \
    if (DS) { STGBR(T1, 0); STGBR(T1, 1); } \
    BARR(); LGKM0(); \
    __builtin_amdgcn_s_setprio(1); \
    _Pragma("unroll") for (int i = 0; i < 4; ++i) \
      _Pragma("unroll") for (int j = 0; j < 3; ++j) acc[4 + i][j] = mfma16h(ag_[i], bf_[j], acc[4 + i][j]); \
    __builtin_amdgcn_s_setprio(0); \
    W2X; \
    BARR(); \
    /* ---- phase 3: i0..3 x j0..2, k-step 1; stage A(t+1) s1 (2) ---- */ \
    _Pragma("unroll") for (int i = 0; i < 4; ++i) af_[i] = *(const short8*)(bp_ + 16384 + abyte[i]); \
    _Pragma("unroll") for (int j = 0; j < 3; ++j) bf_[j] = *(const short8*)(bp_ + 12288 + bbyte[j]); \
    if (DS) STGA(T1, 1); \
    BARR(); LGKM0(); \
    __builtin_amdgcn_s_setprio(1); \
    _Pragma("unroll") for (int i = 0; i < 4; ++i) \
      _Pragma("unroll") for (int j = 0; j < 3; ++j) acc[i][j] = mfma16h(af_[i], bf_[j], acc[i][j]); \
    __builtin_amdgcn_s_setprio(0); \
    BARR(); \
    /* ---- phase 4: i4..7 x j0..2, k-step 1; stage B(t+1) round 2 (1) ---- */ \
    _Pragma("unroll") for (int i = 0; i < 4; ++i) ag_[i] = *(const short8*)(bp_ + 16384 + abyte[4 + i]); \
    if (DS) STGBR(T1, 2); \
    BARR(); LGKM0(); \
    __builtin_amdgcn_s_setprio(1); \
    _Pragma("unroll") for (int i = 0; i < 4; ++i) \
      _Pragma("unroll") for (int j = 0; j < 3; ++j) acc[4 + i][j] = mfma16h(ag_[i], bf_[j], acc[4 + i][j]); \
    __builtin_amdgcn_s_setprio(0); \
    W4X; \
    BARR(); \
  } while (0)

#pragma unroll 1
  for (int t = 0; t < NT - 2; t += 2) {
    TILE(0, 1, t + 1, VMW4(), VMW3());
    TILE(57344, 1, t + 2, VMW4(), VMW3());
  }
  TILE(0, 1, NT - 1, VMW4(), VMW3());
  TILE(57344, 0, 0, VMW0(), (void)0);
#undef TILE
#undef STGA
#undef STGBR
#undef BUFOF

  // epilogue: per-j z (16-col fragments never straddle the 2048 boundary)
#pragma unroll
  for (int j = 0; j < 3; ++j) {
    const int colbase = (int)bn + wn * 48 + j * 16;  // wave-uniform
    const int zj = colbase >> 11;
    const float alpha = (zj == 0) ? alpha_q : 1.0f;
    unsigned short* Cz = C + (size_t)zj * S_LEN * E_DIM;
    const int col = (colbase & 2047) + arow;
    float amxj = 0.f;
#pragma unroll
    for (int i = 0; i < 8; ++i) {
      size_t rowb = bm + wm * 128 + i * 16 + gsl * 4;
#pragma unroll
      for (int r = 0; r < 4; ++r) {
        float v = acc[i][j][r] * alpha;
        Cz[(rowb + r) * E_DIM + col] = f2h(v);
        amxj = fmaxf(amxj, fabsf(v));
      }
    }
#pragma unroll
    for (int off = 32; off; off >>= 1) amxj = fmaxf(amxj, __shfl_xor(amxj, off));
    if (ln == 0) atomicMax(amax + zj, __float_as_uint(amxj));
  }
}

// ========= o-proj: 128x64 tri-buffered INT8 GEMM, XCD-swizzled =========
__global__ __launch_bounds__(256, 4)
void k_gemm_o(const signed char* __restrict__ A, const signed char* __restrict__ Bt,
              float* __restrict__ C, const unsigned* __restrict__ sc,
              const float* __restrict__ wsc) {
  __shared__ char lds[36864];
  const int K = 2048, NT = 32;
  const float sa = fmaxf(__uint_as_float(sc[3]) * (1.f / 127.f), 1e-8f);
  const int lin = blockIdx.y * 16 + blockIdx.x;
  const int swz = (lin & 7) * 64 + (lin >> 3);
  const int iby = swz >> 4;
  const int ibx = swz & 15;

  const int tid = threadIdx.x;
  const int wv = tid >> 6, ln = tid & 63;
  const int wm = wv >> 1, wn = wv & 1;
  const size_t bm = (size_t)ibx * 128, bn = (size_t)iby * 64;
  const int arow = ln & 15, gsl = ln >> 4;

  int abyte[4], bbyte[2];
#pragma unroll
  for (int i = 0; i < 4; ++i) {
    int ra = wm * 64 + i * 16 + arow;
    abyte[i] = ra * 64 + ((gsl ^ ((ra >> 1) & 3)) * 16);
  }
#pragma unroll
  for (int j = 0; j < 2; ++j) {
    int rb = wn * 32 + j * 16 + arow;
    bbyte[j] = rb * 64 + ((gsl ^ ((rb >> 1) & 3)) * 16);
  }

  const int srow = tid >> 2;
  const int sl = (tid & 3) ^ ((srow >> 1) & 3);
  const signed char* Ast = A + (bm + srow) * (size_t)K + sl * 16;
  const signed char* Bst = Bt + (bn + srow) * (size_t)K + sl * 16;

#define STG(T, dst) do { if ((T) < NT) { \
    size_t go = (size_t)(T) * 64; \
    gload_lds16(Ast + go, (dst) + wv * 1024); \
    gload_lds16(Ast + go + (size_t)64 * K, (dst) + 4096 + wv * 1024); \
    gload_lds16(Bst + go, (dst) + 8192 + wv * 1024); } } while (0)

  i32x4 acc[4][2];
#pragma unroll
  for (int i = 0; i < 4; ++i)
#pragma unroll
    for (int j = 0; j < 2; ++j) { acc[i][j][0] = 0; acc[i][j][1] = 0; acc[i][j][2] = 0; acc[i][j][3] = 0; }

  char* b0 = lds;
  char* b1 = lds + 12288;
  char* b2 = lds + 24576;

  STG(0, b0); STG(1, b1);
  VMW3();
  BARR();

#define ITER(T, bufR, bufS) do { \
    i32x4 af[4], bf[2]; \
    _Pragma("unroll") \
    for (int i = 0; i < 4; ++i) af[i] = *(const i32x4*)((bufR) + abyte[i]); \
    _Pragma("unroll") \
    for (int j = 0; j < 2; ++j) bf[j] = *(const i32x4*)((bufR) + 8192 + bbyte[j]); \
    STG((T) + 2, bufS); \
    __builtin_amdgcn_s_setprio(1); \
    _Pragma("unroll") \
    for (int i = 0; i < 4; ++i) \
      _Pragma("unroll") \
      for (int j = 0; j < 2; ++j) acc[i][j] = mfma16i8(af[i], bf[j], acc[i][j]); \
    __builtin_amdgcn_s_setprio(0); \
    if ((T) == NT - 2) { VMW0(); } else if ((T) < NT - 2) { VMW3(); } \
    BARR(); } while (0)

#pragma unroll 1
  for (int t = 0; t + 2 < NT; t += 3) {
    ITER(t, b0, b2);
    ITER(t + 1, b1, b0);
    ITER(t + 2, b2, b1);
  }
  ITER(NT - 2, b0, b2);
  ITER(NT - 1, b1, b0);
#undef ITER
#undef STG

#pragma unroll
  for (int i = 0; i < 4; ++i) {
    size_t rowb = bm + wm * 64 + i * 16 + gsl * 4;
#pragma unroll
    for (int j = 0; j < 2; ++j) {
      size_t col = bn + wn * 32 + j * 16 + arow;
      float s = sa * wsc[col];
#pragma unroll
      for (int r = 0; r < 4; ++r)
        C[(rowb + r) * E_DIM + col] = (float)acc[i][j][r] * s;
    }
  }
}

// ========= merged RoPE(q,k, table-driven) + V-transpose (f16 in/out) =========
__global__ void k_rvt(const unsigned short* __restrict__ qkv,
                      unsigned short* __restrict__ Qh, unsigned short* __restrict__ Kh,
                      unsigned short* __restrict__ Vt, const unsigned* __restrict__ sc,
                      const float2* __restrict__ trig) {
  __shared__ float tb[64][65];
  const int z = blockIdx.z;
  if (z < 2) {
    const unsigned short* x = qkv + (z ? 4194304 : 0);
    unsigned short* out = z ? Kh : Qh;
    float scale = fmaxf(__uint_as_float(sc[z]) * (1.f / 127.f), 1e-8f);
    float invs = 1.f / scale;
    int h = blockIdx.y;
    int s = blockIdx.x * 8 + (threadIdx.x >> 5);
    int i = threadIdx.x & 31;
    size_t base = (size_t)s * E_DIM + h * 64 + i;
    float x0 = h2f(x[base]);
    float x1 = h2f(x[base + 32]);
    float q0 = fq1(x0, invs, scale);
    float q1 = fq1(x1, invs, scale);
    float2 t = trig[s * 32 + i];
    size_t ob = (size_t)h * S_LEN * D_DIM + (size_t)s * D_DIM + i;
    out[ob] = f2h(q0 * t.x - q1 * t.y);
    out[ob + 32] = f2h(q1 * t.x + q0 * t.y);
    return;
  }
  if (blockIdx.x >= 32) return;
  const unsigned short* v = qkv + 2 * 4194304;
  float scale = fmaxf(__uint_as_float(sc[2]) * (1.f / 127.f), 1e-8f);
  float invs = 1.f / scale;
  int s0 = blockIdx.x * 64, h = blockIdx.y;
#pragma unroll
  for (int l = 0; l < 16; ++l) {
    int idx = threadIdx.x + l * 256;
    int r = idx >> 6, c = idx & 63;
    float x = h2f(v[(size_t)(s0 + r) * E_DIM + h * 64 + c]);
    tb[r][c] = fq1(x, invs, scale);
  }
  __syncthreads();
#pragma unroll
  for (int l = 0; l < 16; ++l) {
    int idx = threadIdx.x + l * 256;
    int d = idx >> 6, s = idx & 63;
    Vt[(size_t)h * D_DIM * S_LEN + (size_t)d * S_LEN + s0 + s] = f2h(tb[s][d]);
  }
}

// -------- causal flash attention: 40KB LDS -> 4 blocks/CU (16 waves/CU) --------
__global__ __launch_bounds__(256, 4)
void k_attn(const unsigned short* __restrict__ Qh, const unsigned short* __restrict__ Kh,
            const unsigned short* __restrict__ Vt, unsigned short* __restrict__ att,
            unsigned* __restrict__ amax) {
  __shared__ char Kbuf[2 * 8192];
  __shared__ char Vbuf[2 * 8192];
  __shared__ __align__(16) char Pb[8192];
  const int L = blockIdx.x;
  const int h = L & 31;
  const int qc = 31 - (L >> 5);
  const int nt = qc + 1;
  const int tid = threadIdx.x;
  const int wv = tid >> 6, ln = tid & 63;
  const int arow = ln & 15, gsl = ln >> 4;
  const unsigned short* Qb = Qh + (size_t)h * S_LEN * D_DIM;
  const unsigned short* Kb = Kh + (size_t)h * S_LEN * D_DIM;
  const unsigned short* Vb = Vt + (size_t)h * D_DIM * S_LEN;
  const int qr = qc * 64 + wv * 16;

  const int srow0 = tid >> 3, sch0 = (tid & 7) ^ (srow0 & 7);
  const int srow1 = 32 + (tid >> 3), sch1 = (tid & 7) ^ (srow1 & 7);

#define STAGEK(T, B) do { char* kd = Kbuf + (B) * 8192; const int tb_ = (T) * 64; \
    gload_lds16(Kb + (size_t)(tb_ + srow0) * D_DIM + sch0 * 8, kd + wv * 1024); \
    gload_lds16(Kb + (size_t)(tb_ + srow1) * D_DIM + sch1 * 8, kd + 4096 + wv * 1024); } while (0)
#define STAGEV(T, B) do { char* vd = Vbuf + (B) * 8192; const int tb_ = (T) * 64; \
    gload_lds16(Vb + (size_t)srow0 * S_LEN + tb_ + sch0 * 8, vd + wv * 1024); \
    gload_lds16(Vb + (size_t)srow1 * S_LEN + tb_ + sch1 * 8, vd + 4096 + wv * 1024); } while (0)

  short8 qa0 = *(const short8*)(Qb + (size_t)(qr + arow) * D_DIM + gsl * 8);
  short8 qa1 = *(const short8*)(Qb + (size_t)(qr + arow) * D_DIM + 32 + gsl * 8);

  f32x4 o[4];
  float mrow = -INFINITY, lrow = 0.f;
#pragma unroll
  for (int d = 0; d < 4; ++d) { o[d][0] = 0.f; o[d][1] = 0.f; o[d][2] = 0.f; o[d][3] = 0.f; }

  STAGEK(0, 0);
  STAGEV(0, 0);
  if (nt > 1) { STAGEK(1, 1); STAGEV(1, 1); VMW4(); } else { VMW0(); }
  BARR();

  char* Pw = Pb + wv * 2048 + arow * 128;
  const int arw7 = arow & 7;

#pragma unroll 1
  for (int t = 0; t < nt; ++t) {
    if (t >= 1 && t + 1 < nt) { STAGEK(t + 1, (t + 1) & 1); STAGEV(t + 1, (t + 1) & 1); }
    char* kb = Kbuf + (t & 1) * 8192;
    char* vb = Vbuf + (t & 1) * 8192;

    short8 kf[4][2];
#pragma unroll
    for (int kvb = 0; kvb < 4; ++kvb) {
      int row = kvb * 16 + arow;
      int sw = (row & 7) << 4;
      kf[kvb][0] = *(const short8*)(kb + row * 128 + ((gsl * 16) ^ sw));
      kf[kvb][1] = *(const short8*)(kb + row * 128 + ((64 + gsl * 16) ^ sw));
    }
    f32x4 s4[4];
#pragma unroll
    for (int kvb = 0; kvb < 4; ++kvb) {
      s4[kvb][0] = 0.f; s4[kvb][1] = 0.f; s4[kvb][2] = 0.f; s4[kvb][3] = 0.f;
    }
#pragma unroll
    for (int kvb = 0; kvb < 4; ++kvb) {
      s4[kvb] = mfma16h(kf[kvb][0], qa0, s4[kvb]);
      s4[kvb] = mfma16h(kf[kvb][1], qa1, s4[kvb]);
    }

    const int t0 = t * 64;
    const int qrow = qr + arow;
    if (t0 + 63 > qrow) {
#pragma unroll
      for (int kvb = 0; kvb < 4; ++kvb) {
        int colb = t0 + kvb * 16 + gsl * 4;
#pragma unroll
        for (int r = 0; r < 4; ++r)
          if (colb + r > qrow) s4[kvb][r] = -INFINITY;
      }
    }

    float smax = s4[0][0];
#pragma unroll
    for (int kvb = 0; kvb < 4; ++kvb)
#pragma unroll
      for (int r = 0; r < 4; ++r) smax = fmaxf(smax, s4[kvb][r]);
    smax = fmaxf(smax, __shfl_xor(smax, 16));
    smax = fmaxf(smax, __shfl_xor(smax, 32));

    float mn = fmaxf(mrow, smax);
    float corr = __expf(mrow - mn);
    mrow = mn;

    float rs = 0.f;
    float p[4][4];
#pragma unroll
    for (int kvb = 0; kvb < 4; ++kvb)
#pragma unroll
      for (int r = 0; r < 4; ++r) {
        p[kvb][r] = __expf(s4[kvb][r] - mn);
        rs += p[kvb][r];
      }
    rs += __shfl_xor(rs, 16);
    rs += __shfl_xor(rs, 32);
    lrow = lrow * corr + rs;

    float corr_r[4];
#pragma unroll
    for (int r = 0; r < 4; ++r) corr_r[r] = __shfl(corr, gsl * 4 + r);
#pragma unroll
    for (int d = 0; d < 4; ++d)
#pragma unroll
      for (int r = 0; r < 4; ++r) o[d][r] *= corr_r[r];

    __builtin_amdgcn_wave_barrier();
#pragma unroll
    for (int kvb = 0; kvb < 4; ++kvb) {
      short4v pw;
      pw[0] = (short)f2h(p[kvb][0]);
      pw[1] = (short)f2h(p[kvb][1]);
      pw[2] = (short)f2h(p[kvb][2]);
      pw[3] = (short)f2h(p[kvb][3]);
      const int u = kvb * 2 + (gsl >> 1);
      *(short4v*)(Pw + ((u ^ arw7) << 4) + ((gsl & 1) << 3)) = pw;
    }
    __builtin_amdgcn_wave_barrier();
    short8 pa0 = *(const short8*)(Pw + ((gsl ^ arw7) << 4));
    short8 pa1 = *(const short8*)(Pw + (((4 + gsl) ^ arw7) << 4));
    __builtin_amdgcn_wave_barrier();

    short8 vf[4][2];
#pragma unroll
    for (int d = 0; d < 4; ++d) {
      int row = d * 16 + arow;
      int sw = (row & 7) << 4;
      vf[d][0] = *(const short8*)(vb + row * 128 + ((gsl * 16) ^ sw));
      vf[d][1] = *(const short8*)(vb + row * 128 + ((64 + gsl * 16) ^ sw));
    }
#pragma unroll
    for (int d = 0; d < 4; ++d) {
      o[d] = mfma16h(pa0, vf[d][0], o[d]);
      o[d] = mfma16h(pa1, vf[d][1], o[d]);
    }

    VMW0();
    BARR();
  }
#undef STAGEK
#undef STAGEV

  float amx = 0.f;
  float invl = 1.f / lrow;
  float invl_r[4];
#pragma unroll
  for (int r = 0; r < 4; ++r) invl_r[r] = __shfl(invl, gsl * 4 + r);
#pragma unroll
  for (int r = 0; r < 4; ++r) {
    size_t row = (size_t)(qr + gsl * 4 + r);
#pragma unroll
    for (int d = 0; d < 4; ++d) {
      float v = o[d][r] * invl_r[r];
      att[row * E_DIM + h * 64 + d * 16 + arow] = f2h(v);
      amx = fmaxf(amx, fabsf(v));
    }
  }

#pragma unroll
  for (int off = 32; off; off >>= 1) amx = fmaxf(amx, __shfl_xor(amx, off));
  if (ln == 0) atomicMax(amax + 3, __float_as_uint(amx));
}

// ---------------- act fake-quant f16 -> packed int8 (8 elems/thread) ----------------
__global__ void k_quant_act_i8(const unsigned short* __restrict__ in, uint2* __restrict__ out,
                               const unsigned* __restrict__ sc, int idx) {
  float scale = fmaxf(__uint_as_float(sc[idx]) * (1.f / 127.f), 1e-8f);
  float invs = 1.f / scale;
  int i = blockIdx.x * blockDim.x + threadIdx.x;
  short8 v = ((const short8*)in)[i];
  unsigned lo = 0, hi = 0;
#pragma unroll
  for (int e = 0; e < 4; ++e)
    lo |= (unsigned)(q8(h2f((unsigned short)v[e]), invs) & 255) << (8 * e);
#pragma unroll
  for (int e = 0; e < 4; ++e)
    hi |= (unsigned)(q8(h2f((unsigned short)v[4 + e]), invs) & 255) << (8 * e);
  uint2 pk; pk.x = lo; pk.y = hi;
  out[i] = pk;
}

extern "C" void kernel_launch(void* const* d_in, const int* in_sizes, int n_in,
                              void* d_out, int out_size, void* d_ws, size_t ws_size,
                              hipStream_t stream) {
  const float* hs = (const float*)d_in[0];
  const float* w_q = (const float*)d_in[1];
  const float* w_k = (const float*)d_in[2];
  const float* w_v = (const float*)d_in[3];
  const float* w_o = (const float*)d_in[4];

  char* ws = (char*)d_ws;
  unsigned short* wq_all = (unsigned short*)(ws);                 // 3 x E*E f16 (q,k,v)
  signed char* wo_i8 = (signed char*)(ws + 25165824);             // E*E i8
  float* wsc = (float*)(ws + 29360128);                           // 2048 f32
  float2* trig = (float2*)(ws + 30408704);                        // 65536 float2 (512KB)
  unsigned short* hsb = (unsigned short*)(ws + 33554432);         // S*E f16
  unsigned short* qkv16 = (unsigned short*)(ws + 41943040);       // 3 x S*E f16
  unsigned short* att = qkv16;                                    // alias q slab (f16)
  signed char* aq_i8 = (signed char*)(ws + 67108864);             // S*E i8
  unsigned short* Qh = (unsigned short*)(ws + 92274688);          // [H][S][D] f16
  unsigned short* Kh = (unsigned short*)(ws + 100663296);
  unsigned short* Vt = (unsigned short*)(ws + 109051904);         // [H][D][S] f16
  unsigned* sc = (unsigned*)(ws + 117440512);                     // absmax scalars

  k_prep<<<12545, 256, 0, stream>>>(hs, w_q, w_k, w_v, w_o, hsb, wq_all, wo_i8, wsc, sc, trig);
  k_gemm_qkv<<<dim3(256), 512, 0, stream>>>(hsb, wq_all, qkv16, sc, 0.125f);
  k_rvt<<<dim3(256, 32, 3), 256, 0, stream>>>(qkv16, Qh, Kh, Vt, sc, trig);
  k_attn<<<1024, 256, 0, stream>>>(Qh, Kh, Vt, att, sc);
  k_quant_act_i8<<<2048, 256, 0, stream>>>(att, (uint2*)aq_i8, sc, 3);
  k_gemm_o<<<dim3(16, 32), 256, 0, stream>>>(aq_i8, wo_i8, (float*)d_out, sc, wsc);
}

// Round 6
// 184.913 us; speedup vs baseline: 1.2991x; 1.2844x over previous
//
#include <hip/hip_runtime.h>
#include <hip/hip_bf16.h>
#include <hip/hip_fp16.h>

#define S_LEN 2048
#define E_DIM 2048
#define H_NUM 32
#define D_DIM 64

typedef __attribute__((ext_vector_type(8))) short short8;
typedef __attribute__((ext_vector_type(4))) short short4v;
typedef __attribute__((ext_vector_type(4))) float f32x4;
typedef __attribute__((ext_vector_type(4))) int i32x4;

__device__ __forceinline__ unsigned short f2h(float f) {
  return __builtin_bit_cast(unsigned short, (_Float16)f);
}

__device__ __forceinline__ float h2f(unsigned short u) {
  return (float)__builtin_bit_cast(_Float16, u);
}

__device__ __forceinline__ float fq1(float x, float invs, float scale) {
  return fminf(fmaxf(rintf(x * invs), -128.f), 127.f) * scale;
}

__device__ __forceinline__ int q8(float x, float invs) {
  return min(max((int)rintf(x * invs), -128), 127);
}

__device__ __forceinline__ void gload_lds16(const void* g, void* l) {
  __builtin_amdgcn_global_load_lds((const __attribute__((address_space(1))) void*)g,
                                   (__attribute__((address_space(3))) void*)l, 16, 0, 0);
}

__device__ __forceinline__ f32x4 mfma16h(short8 a, short8 b, f32x4 c) {
  return __builtin_amdgcn_mfma_f32_16x16x32_f16(a, b, c, 0, 0, 0);
}

__device__ __forceinline__ i32x4 mfma16i8(i32x4 a, i32x4 b, i32x4 c) {
  return __builtin_amdgcn_mfma_i32_16x16x64_i8(a, b, c, 0, 0, 0);
}

#define VMW4() asm volatile("s_waitcnt vmcnt(4)" ::: "memory")
#define VMW3() asm volatile("s_waitcnt vmcnt(3)" ::: "memory")
#define VMW0() asm volatile("s_waitcnt vmcnt(0)" ::: "memory")
#define BARR() asm volatile("s_barrier" ::: "memory")
#define LGKM0() asm volatile("s_waitcnt lgkmcnt(0)" ::: "memory")

// ========= merged prologue: cvt + quant_w + quant_wo + sc init + RoPE table =========
// blocks [0,4096): hs cvt; [4096,10240): w_{q,k,v}; [10240,12288): w_o->i8;
// b==12288: sc init; [12289,12545): cos/sin table (65536 (s,i) pairs, f32x2).
__global__ void k_prep(const float* __restrict__ hs,
                       const float* __restrict__ w_q, const float* __restrict__ w_k,
                       const float* __restrict__ w_v, const float* __restrict__ w_o,
                       unsigned short* __restrict__ hsb, unsigned short* __restrict__ wq_all,
                       signed char* __restrict__ wo_i8, float* __restrict__ wsc,
                       unsigned* __restrict__ sc, float2* __restrict__ trig) {
  const int b = blockIdx.x;
  if (b < 4096) {
    int i = b * 256 + threadIdx.x;
    float4 v = ((const float4*)hs)[i];
    ushort4 r;
    r.x = f2h(v.x); r.y = f2h(v.y); r.z = f2h(v.z); r.w = f2h(v.w);
    ((ushort4*)hsb)[i] = r;
    return;
  }
  if (b >= 12288) {
    if (b == 12288) {
      if (threadIdx.x < 8) sc[threadIdx.x] = 0u;
      return;
    }
    // trig table: idx = (b-12289)*256 + tid -> s = idx>>5, i = idx&31
    int idx = (b - 12289) * 256 + threadIdx.x;
    int s = idx >> 5, i = idx & 31;
    float freq = exp2f(-(float)i * (13.287712379549449f / 32.f));
    float ang = (float)s * freq;
    float sn, cs;
    sincosf(ang, &sn, &cs);
    float2 t; t.x = cs; t.y = sn;
    trig[idx] = t;
    return;
  }
  __shared__ float wm[4];
  const int isWo = (b >= 10240);
  const int bb = isWo ? (b - 10240) : (b - 4096);
  const int wy = isWo ? 0 : (bb >> 11);
  const int wx = isWo ? bb : (bb & 2047);
  const float* w = isWo ? w_o : (wy == 0 ? w_q : wy == 1 ? w_k : w_v);
  const float* row = w + (size_t)wx * E_DIM;
  float4 a = ((const float4*)row)[threadIdx.x * 2];
  float4 bq = ((const float4*)row)[threadIdx.x * 2 + 1];
  float m = fmaxf(fmaxf(fmaxf(fabsf(a.x), fabsf(a.y)), fmaxf(fabsf(a.z), fabsf(a.w))),
                  fmaxf(fmaxf(fabsf(bq.x), fabsf(bq.y)), fmaxf(fabsf(bq.z), fabsf(bq.w))));
#pragma unroll
  for (int off = 32; off; off >>= 1) m = fmaxf(m, __shfl_xor(m, off));
  if ((threadIdx.x & 63) == 0) wm[threadIdx.x >> 6] = m;
  __syncthreads();
  m = fmaxf(fmaxf(wm[0], wm[1]), fmaxf(wm[2], wm[3]));
  float scale = fmaxf(m * (1.f / 127.f), 1e-8f);
  float invs = 1.f / scale;
  if (isWo) {
    unsigned lo = (unsigned)(q8(a.x, invs) & 255) | ((unsigned)(q8(a.y, invs) & 255) << 8) |
                  ((unsigned)(q8(a.z, invs) & 255) << 16) | ((unsigned)(q8(a.w, invs) & 255) << 24);
    unsigned hi = (unsigned)(q8(bq.x, invs) & 255) | ((unsigned)(q8(bq.y, invs) & 255) << 8) |
                  ((unsigned)(q8(bq.z, invs) & 255) << 16) | ((unsigned)(q8(bq.w, invs) & 255) << 24);
    uint2 pk; pk.x = lo; pk.y = hi;
    ((uint2*)(wo_i8 + (size_t)wx * E_DIM))[threadIdx.x] = pk;
    if (threadIdx.x == 0) wsc[wx] = scale;
  } else {
    unsigned short* orow = wq_all + (size_t)wy * E_DIM * E_DIM + (size_t)wx * E_DIM;
    ushort4 r0, r1;
    r0.x = f2h(fq1(a.x, invs, scale)); r0.y = f2h(fq1(a.y, invs, scale));
    r0.z = f2h(fq1(a.z, invs, scale)); r0.w = f2h(fq1(a.w, invs, scale));
    r1.x = f2h(fq1(bq.x, invs, scale)); r1.y = f2h(fq1(bq.y, invs, scale));
    r1.z = f2h(fq1(bq.z, invs, scale)); r1.w = f2h(fq1(bq.w, invs, scale));
    ((ushort4*)orow)[threadIdx.x * 2] = r0;
    ((ushort4*)orow)[threadIdx.x * 2 + 1] = r1;
  }
}

// ========= 256x256 8-phase double-buffered f16 GEMM (QKV z-fused), XCD-swizzled ======
// PROVEN R0 version (76.2 us, MfmaUtil 27, FETCH 45MB): 512 threads = 8 waves
// (2M x 4N), BK=64 (2 K-steps/tile), LDS 128 KiB. Counted vmcnt(4) twice per
// K-tile (phases 2 and 4); every wait drains only loads issued >=2 phases ago.
__global__ __launch_bounds__(512, 2)
void k_gemm_qkv(const unsigned short* __restrict__ A, const unsigned short* __restrict__ Bt,
                unsigned short* __restrict__ C, unsigned* __restrict__ amax, float alpha_q) {
  __shared__ char lds[131072];
  const int K = 2048, NT = 32;
  // bijective XCD swizzle: 192 wgs, 192 % 8 == 0, 24 per XCD
  const int lin = blockIdx.x;
  const int swz = (lin & 7) * 24 + (lin >> 3);
  const int z = swz >> 6;
  const int t64 = swz & 63;
  const int iby = t64 >> 3;
  const int ibx = t64 & 7;
  const unsigned short* Bz = Bt + (size_t)z * E_DIM * E_DIM;
  unsigned short* Cz = C + (size_t)z * S_LEN * E_DIM;
  const float alpha = (z == 0) ? alpha_q : 1.0f;

  const int tid = threadIdx.x;
  const int wv = tid >> 6, ln = tid & 63;
  const int wm = wv >> 2, wn = wv & 3;
  const size_t bm = (size_t)ibx * 256, bn = (size_t)iby * 256;
  const int arow = ln & 15, gsl = ln >> 4;

  // LDS read byte offsets within one 64KB buffer (A: +s*16384; B: +32768+s*16384)
  int abyte[8], bbyte[4];
#pragma unroll
  for (int i = 0; i < 8; ++i) {
    int r = wm * 128 + i * 16 + arow;
    abyte[i] = r * 64 + ((gsl ^ ((r >> 1) & 3)) * 16);
  }
#pragma unroll
  for (int j = 0; j < 4; ++j) {
    int r = wn * 64 + j * 16 + arow;
    bbyte[j] = 32768 + r * 64 + ((gsl ^ ((r >> 1) & 3)) * 16);
  }

  // staging: thread tid covers rows (tid>>2) and (tid>>2)+128 of a 256x32 chunk;
  // pre-swizzled global source chunk so linear LDS dest + swizzled read agree
  const int srow = tid >> 2;
  const int scc = (tid & 3) ^ ((tid >> 3) & 3);
  const unsigned short* Asrc = A + (bm + srow) * (size_t)K + scc * 8;
  const unsigned short* Bsrc = Bz + (bn + srow) * (size_t)K + scc * 8;
  const int ldst = tid * 16;

#define STGA(T, S) do { \
    char* d_ = lds + ((T) & 1) * 65536 + (S) * 16384 + ldst; \
    const unsigned short* s_ = Asrc + (T) * 64 + (S) * 32; \
    gload_lds16(s_, d_); \
    gload_lds16(s_ + (size_t)128 * K, d_ + 8192); } while (0)
#define STGB(T, S) do { \
    char* d_ = lds + ((T) & 1) * 65536 + 32768 + (S) * 16384 + ldst; \
    const unsigned short* s_ = Bsrc + (T) * 64 + (S) * 32; \
    gload_lds16(s_, d_); \
    gload_lds16(s_ + (size_t)128 * K, d_ + 8192); } while (0)

  f32x4 acc[8][4];
#pragma unroll
  for (int i = 0; i < 8; ++i)
#pragma unroll
    for (int j = 0; j < 4; ++j) { acc[i][j][0] = 0.f; acc[i][j][1] = 0.f; acc[i][j][2] = 0.f; acc[i][j][3] = 0.f; }

  // prologue: tile 0 chunks (A-s0, B-s0, A-s1, B-s1); wait first two chunks
  STGA(0, 0); STGB(0, 0); STGA(0, 1); STGB(0, 1);
  VMW4();
  BARR();

  // One K-tile = 4 phases x 16 MFMA. DS: stage tile T1 into the other buffer.
  // W2X after phase-2 MFMA (guards this tile's s1 chunks), W4X after phase-4
  // MFMA (guards next tile's s0 chunks). Both vmcnt(4) in steady state.
#define TILE(BUF, DS, T1, W2X, W4X) do { \
    char* bp_ = lds + (BUF); \
    short8 af_[4], bf_[4], ag_[4]; \
    /* ---- phase 1: i0..3 x j0..3, k-step 0 ---- */ \
    _Pragma("unroll") for (int i = 0; i < 4; ++i) af_[i] = *(const short8*)(bp_ + abyte[i]); \
    _Pragma("unroll") for (int j = 0; j < 4; ++j) bf_[j] = *(const short8*)(bp_ + bbyte[j]); \
    if (DS) STGA(T1, 0); \
    BARR(); LGKM0(); \
    __builtin_amdgcn_s_setprio(1); \
    _Pragma("unroll") for (int i = 0; i < 4; ++i) \
      _Pragma("unroll") for (int j = 0; j < 4; ++j) acc[i][j] = mfma16h(af_[i], bf_[j], acc[i][j]); \
    __builtin_amdgcn_s_setprio(0); \
    BARR(); \
    /* ---- phase 2: i4..7 x j0..3, k-step 0 ---- */ \
    _Pragma("unroll") for (int i = 0; i < 4; ++i) ag_[i] = *(const short8*)(bp_ + abyte[4 + i]); \
    if (DS) STGB(T1, 0); \
    BARR(); LGKM0(); \
    __builtin_amdgcn_s_setprio(1); \
    _Pragma("unroll") for (int i = 0; i < 4; ++i) \
      _Pragma("unroll") for (int j = 0; j < 4; ++j) acc[4 + i][j] = mfma16h(ag_[i], bf_[j], acc[4 + i][j]); \
    __builtin_amdgcn_s_setprio(0); \
    W2X; \
    BARR(); \
    /* ---- phase 3: i0..3 x j0..3, k-step 1 ---- */ \
    _Pragma("unroll") for (int i = 0; i < 4; ++i) af_[i] = *(const short8*)(bp_ + 16384 + abyte[i]); \
    _Pragma("unroll") for (int j = 0; j < 4; ++j) bf_[j] = *(const short8*)(bp_ + 16384 + bbyte[j]); \
    if (DS) STGA(T1, 1); \
    BARR(); LGKM0(); \
    __builtin_amdgcn_s_setprio(1); \
    _Pragma("unroll") for (int i = 0; i < 4; ++i) \
      _Pragma("unroll") for (int j = 0; j < 4; ++j) acc[i][j] = mfma16h(af_[i], bf_[j], acc[i][j]); \
    __builtin_amdgcn_s_setprio(0); \
    BARR(); \
    /* ---- phase 4: i4..7 x j0..3, k-step 1 ---- */ \
    _Pragma("unroll") for (int i = 0; i < 4; ++i) ag_[i] = *(const short8*)(bp_ + 16384 + abyte[4 + i]); \
    if (DS) STGB(T1, 1); \
    BARR(); LGKM0(); \
    __builtin_amdgcn_s_setprio(1); \
    _Pragma("unroll") for (int i = 0; i < 4; ++i) \
      _Pragma("unroll") for (int j = 0; j < 4; ++j) acc[4 + i][j] = mfma16h(ag_[i], bf_[j], acc[4 + i][j]); \
    __builtin_amdgcn_s_setprio(0); \
    W4X; \
    BARR(); \
  } while (0)

#pragma unroll 1
  for (int t = 0; t < NT - 2; t += 2) {
    TILE(0, 1, t + 1, VMW4(), VMW4());
    TILE(65536, 1, t + 2, VMW4(), VMW4());
  }
  TILE(0, 1, NT - 1, VMW4(), VMW4());
  TILE(65536, 0, 0, VMW0(), (void)0);
#undef TILE
#undef STGA
#undef STGB

  float amx = 0.f;
#pragma unroll
  for (int i = 0; i < 8; ++i) {
    size_t rowb = bm + wm * 128 + i * 16 + gsl * 4;
#pragma unroll
    for (int j = 0; j < 4; ++j) {
      size_t col = bn + wn * 64 + j * 16 + arow;
#pragma unroll
      for (int r = 0; r < 4; ++r) {
        float v = acc[i][j][r] * alpha;
        Cz[(rowb + r) * E_DIM + col] = f2h(v);
        amx = fmaxf(amx, fabsf(v));
      }
    }
  }
#pragma unroll
  for (int off = 32; off; off >>= 1) amx = fmaxf(amx, __shfl_xor(amx, off));
  if (ln == 0) atomicMax(amax + z, __float_as_uint(amx));
}

// ========= o-proj: 128x64 tri-buffered INT8 GEMM, XCD-swizzled =========
__global__ __launch_bounds__(256, 4)
void k_gemm_o(const signed char* __restrict__ A, const signed char* __restrict__ Bt,
              float* __restrict__ C, const unsigned* __restrict__ sc,
              const float* __restrict__ wsc) {
  __shared__ char lds[36864];
  const int K = 2048, NT = 32;
  const float sa = fmaxf(__uint_as_float(sc[3]) * (1.f / 127.f), 1e-8f);
  const int lin = blockIdx.y * 16 + blockIdx.x;
  const int swz = (lin & 7) * 64 + (lin >> 3);
  const int iby = swz >> 4;
  const int ibx = swz & 15;

  const int tid = threadIdx.x;
  const int wv = tid >> 6, ln = tid & 63;
  const int wm = wv >> 1, wn = wv & 1;
  const size_t bm = (size_t)ibx * 128, bn = (size_t)iby * 64;
  const int arow = ln & 15, gsl = ln >> 4;

  int abyte[4], bbyte[2];
#pragma unroll
  for (int i = 0; i < 4; ++i) {
    int ra = wm * 64 + i * 16 + arow;
    abyte[i] = ra * 64 + ((gsl ^ ((ra >> 1) & 3)) * 16);
  }
#pragma unroll
  for (int j = 0; j < 2; ++j) {
    int rb = wn * 32 + j * 16 + arow;
    bbyte[j] = rb * 64 + ((gsl ^ ((rb >> 1) & 3)) * 16);
  }

  const int srow = tid >> 2;
  const int sl = (tid & 3) ^ ((srow >> 1) & 3);
  const signed char* Ast = A + (bm + srow) * (size_t)K + sl * 16;
  const signed char* Bst = Bt + (bn + srow) * (size_t)K + sl * 16;

#define STG(T, dst) do { if ((T) < NT) { \
    size_t go = (size_t)(T) * 64; \
    gload_lds16(Ast + go, (dst) + wv * 1024); \
    gload_lds16(Ast + go + (size_t)64 * K, (dst) + 4096 + wv * 1024); \
    gload_lds16(Bst + go, (dst) + 8192 + wv * 1024); } } while (0)

  i32x4 acc[4][2];
#pragma unroll
  for (int i = 0; i < 4; ++i)
#pragma unroll
    for (int j = 0; j < 2; ++j) { acc[i][j][0] = 0; acc[i][j][1] = 0; acc[i][j][2] = 0; acc[i][j][3] = 0; }

  char* b0 = lds;
  char* b1 = lds + 12288;
  char* b2 = lds + 24576;

  STG(0, b0); STG(1, b1);
  VMW3();
  BARR();

#define ITER(T, bufR, bufS) do { \
    i32x4 af[4], bf[2]; \
    _Pragma("unroll") \
    for (int i = 0; i < 4; ++i) af[i] = *(const i32x4*)((bufR) + abyte[i]); \
    _Pragma("unroll") \
    for (int j = 0; j < 2; ++j) bf[j] = *(const i32x4*)((bufR) + 8192 + bbyte[j]); \
    STG((T) + 2, bufS); \
    __builtin_amdgcn_s_setprio(1); \
    _Pragma("unroll") \
    for (int i = 0; i < 4; ++i) \
      _Pragma("unroll") \
      for (int j = 0; j < 2; ++j) acc[i][j] = mfma16i8(af[i], bf[j], acc[i][j]); \
    __builtin_amdgcn_s_setprio(0); \
    if ((T) == NT - 2) { VMW0(); } else if ((T) < NT - 2) { VMW3(); } \
    BARR(); } while (0)

#pragma unroll 1
  for (int t = 0; t + 2 < NT; t += 3) {
    ITER(t, b0, b2);
    ITER(t + 1, b1, b0);
    ITER(t + 2, b2, b1);
  }
  ITER(NT - 2, b0, b2);
  ITER(NT - 1, b1, b0);
#undef ITER
#undef STG

#pragma unroll
  for (int i = 0; i < 4; ++i) {
    size_t rowb = bm + wm * 64 + i * 16 + gsl * 4;
#pragma unroll
    for (int j = 0; j < 2; ++j) {
      size_t col = bn + wn * 32 + j * 16 + arow;
      float s = sa * wsc[col];
#pragma unroll
      for (int r = 0; r < 4; ++r)
        C[(rowb + r) * E_DIM + col] = (float)acc[i][j][r] * s;
    }
  }
}

// ========= merged RoPE(q,k, table-driven, VECTORIZED) + V-transpose (f16) =========
// q/k path (z<2): 64 blocks x 32 rows. Each thread owns 8 contiguous dims
// (one short8 load + one short8 store); rotate-half partner (i <-> i+32) comes
// from lane tid^4 via 4x shfl_xor (lanes j and j^4 hold the two halves of the
// same row). 8x fewer memory instructions than the scalar-2B version.
__global__ void k_rvt(const unsigned short* __restrict__ qkv,
                      unsigned short* __restrict__ Qh, unsigned short* __restrict__ Kh,
                      unsigned short* __restrict__ Vt, const unsigned* __restrict__ sc,
                      const float2* __restrict__ trig) {
  __shared__ float tb[64][65];
  const int z = blockIdx.z;
  if (z < 2) {
    const unsigned short* x = qkv + (z ? 4194304 : 0);
    unsigned short* out = z ? Kh : Qh;
    float scale = fmaxf(__uint_as_float(sc[z]) * (1.f / 127.f), 1e-8f);
    float invs = 1.f / scale;
    const int h = blockIdx.y;
    const int tid = threadIdx.x;
    const int s = blockIdx.x * 32 + (tid >> 3);
    const int j = tid & 7;
    // my 8 raw values: dims [j*8, j*8+8)
    short8 v = *(const short8*)(x + (size_t)s * E_DIM + h * 64 + j * 8);
    // partner (dims +-32): lane tid^4 (same row: tid>>3 unchanged)
    int pi[4];
    {
      const int* vi = (const int*)&v;
#pragma unroll
      for (int w = 0; w < 4; ++w) pi[w] = __shfl_xor(vi[w], 4);
    }
    short8 p = *(const short8*)pi;
    // out[i]    = q0*cos_i - q1*sin_i   (j<4: mine=q0, partner=q1)
    // out[i+32] = q1*cos_i + q0*sin_i   (j>=4: mine=q1, partner=q0)
    const float sgn = (j < 4) ? -1.f : 1.f;
    const float2* tp = trig + s * 32 + (j & 3) * 8;
    short8 ro;
#pragma unroll
    for (int e = 0; e < 8; ++e) {
      float me = fq1(h2f((unsigned short)v[e]), invs, scale);
      float pe = fq1(h2f((unsigned short)p[e]), invs, scale);
      float2 t = tp[e];
      ro[e] = (short)f2h(me * t.x + sgn * (pe * t.y));
    }
    *(short8*)(out + (size_t)h * S_LEN * D_DIM + (size_t)s * D_DIM + j * 8) = ro;
    return;
  }
  if (blockIdx.x >= 32) return;
  const unsigned short* v = qkv + 2 * 4194304;
  float scale = fmaxf(__uint_as_float(sc[2]) * (1.f / 127.f), 1e-8f);
  float invs = 1.f / scale;
  int s0 = blockIdx.x * 64, h = blockIdx.y;
#pragma unroll
  for (int l = 0; l < 16; ++l) {
    int idx = threadIdx.x + l * 256;
    int r = idx >> 6, c = idx & 63;
    float x = h2f(v[(size_t)(s0 + r) * E_DIM + h * 64 + c]);
    tb[r][c] = fq1(x, invs, scale);
  }
  __syncthreads();
#pragma unroll
  for (int l = 0; l < 16; ++l) {
    int idx = threadIdx.x + l * 256;
    int d = idx >> 6, s = idx & 63;
    Vt[(size_t)h * D_DIM * S_LEN + (size_t)d * S_LEN + s0 + s] = f2h(tb[s][d]);
  }
}

// -------- causal flash attention: 40KB LDS -> 4 blocks/CU (16 waves/CU) --------
__global__ __launch_bounds__(256, 4)
void k_attn(const unsigned short* __restrict__ Qh, const unsigned short* __restrict__ Kh,
            const unsigned short* __restrict__ Vt, unsigned short* __restrict__ att,
            unsigned* __restrict__ amax) {
  __shared__ char Kbuf[2 * 8192];
  __shared__ char Vbuf[2 * 8192];
  __shared__ __align__(16) char Pb[8192];
  const int L = blockIdx.x;
  const int h = L & 31;
  const int qc = 31 - (L >> 5);
  const int nt = qc + 1;
  const int tid = threadIdx.x;
  const int wv = tid >> 6, ln = tid & 63;
  const int arow = ln & 15, gsl = ln >> 4;
  const unsigned short* Qb = Qh + (size_t)h * S_LEN * D_DIM;
  const unsigned short* Kb = Kh + (size_t)h * S_LEN * D_DIM;
  const unsigned short* Vb = Vt + (size_t)h * D_DIM * S_LEN;
  const int qr = qc * 64 + wv * 16;

  const int srow0 = tid >> 3, sch0 = (tid & 7) ^ (srow0 & 7);
  const int srow1 = 32 + (tid >> 3), sch1 = (tid & 7) ^ (srow1 & 7);

#define STAGEK(T, B) do { char* kd = Kbuf + (B) * 8192; const int tb_ = (T) * 64; \
    gload_lds16(Kb + (size_t)(tb_ + srow0) * D_DIM + sch0 * 8, kd + wv * 1024); \
    gload_lds16(Kb + (size_t)(tb_ + srow1) * D_DIM + sch1 * 8, kd + 4096 + wv * 1024); } while (0)
#define STAGEV(T, B) do { char* vd = Vbuf + (B) * 8192; const int tb_ = (T) * 64; \
    gload_lds16(Vb + (size_t)srow0 * S_LEN + tb_ + sch0 * 8, vd + wv * 1024); \
    gload_lds16(Vb + (size_t)srow1 * S_LEN + tb_ + sch1 * 8, vd + 4096 + wv * 1024); } while (0)

  short8 qa0 = *(const short8*)(Qb + (size_t)(qr + arow) * D_DIM + gsl * 8);
  short8 qa1 = *(const short8*)(Qb + (size_t)(qr + arow) * D_DIM + 32 + gsl * 8);

  f32x4 o[4];
  float mrow = -INFINITY, lrow = 0.f;
#pragma unroll
  for (int d = 0; d < 4; ++d) { o[d][0] = 0.f; o[d][1] = 0.f; o[d][2] = 0.f; o[d][3] = 0.f; }

  STAGEK(0, 0);
  STAGEV(0, 0);
  if (nt > 1) { STAGEK(1, 1); STAGEV(1, 1); VMW4(); } else { VMW0(); }
  BARR();

  char* Pw = Pb + wv * 2048 + arow * 128;
  const int arw7 = arow & 7;

#pragma unroll 1
  for (int t = 0; t < nt; ++t) {
    if (t >= 1 && t + 1 < nt) { STAGEK(t + 1, (t + 1) & 1); STAGEV(t + 1, (t + 1) & 1); }
    char* kb = Kbuf + (t & 1) * 8192;
    char* vb = Vbuf + (t & 1) * 8192;

    short8 kf[4][2];
#pragma unroll
    for (int kvb = 0; kvb < 4; ++kvb) {
      int row = kvb * 16 + arow;
      int sw = (row & 7) << 4;
      kf[kvb][0] = *(const short8*)(kb + row * 128 + ((gsl * 16) ^ sw));
      kf[kvb][1] = *(const short8*)(kb + row * 128 + ((64 + gsl * 16) ^ sw));
    }
    f32x4 s4[4];
#pragma unroll
    for (int kvb = 0; kvb < 4; ++kvb) {
      s4[kvb][0] = 0.f; s4[kvb][1] = 0.f; s4[kvb][2] = 0.f; s4[kvb][3] = 0.f;
    }
#pragma unroll
    for (int kvb = 0; kvb < 4; ++kvb) {
      s4[kvb] = mfma16h(kf[kvb][0], qa0, s4[kvb]);
      s4[kvb] = mfma16h(kf[kvb][1], qa1, s4[kvb]);
    }

    const int t0 = t * 64;
    const int qrow = qr + arow;
    if (t0 + 63 > qrow) {
#pragma unroll
      for (int kvb = 0; kvb < 4; ++kvb) {
        int colb = t0 + kvb * 16 + gsl * 4;
#pragma unroll
        for (int r = 0; r < 4; ++r)
          if (colb + r > qrow) s4[kvb][r] = -INFINITY;
      }
    }

    float smax = s4[0][0];
#pragma unroll
    for (int kvb = 0; kvb < 4; ++kvb)
#pragma unroll
      for (int r = 0; r < 4; ++r) smax = fmaxf(smax, s4[kvb][r]);
    smax = fmaxf(smax, __shfl_xor(smax, 16));
    smax = fmaxf(smax, __shfl_xor(smax, 32));

    float mn = fmaxf(mrow, smax);
    float corr = __expf(mrow - mn);
    mrow = mn;

    float rs = 0.f;
    float p[4][4];
#pragma unroll
    for (int kvb = 0; kvb < 4; ++kvb)
#pragma unroll
      for (int r = 0; r < 4; ++r) {
        p[kvb][r] = __expf(s4[kvb][r] - mn);
        rs += p[kvb][r];
      }
    rs += __shfl_xor(rs, 16);
    rs += __shfl_xor(rs, 32);
    lrow = lrow * corr + rs;

    float corr_r[4];
#pragma unroll
    for (int r = 0; r < 4; ++r) corr_r[r] = __shfl(corr, gsl * 4 + r);
#pragma unroll
    for (int d = 0; d < 4; ++d)
#pragma unroll
      for (int r = 0; r < 4; ++r) o[d][r] *= corr_r[r];

    __builtin_amdgcn_wave_barrier();
#pragma unroll
    for (int kvb = 0; kvb < 4; ++kvb) {
      short4v pw;
      pw[0] = (short)f2h(p[kvb][0]);
      pw[1] = (short)f2h(p[kvb][1]);
      pw[2] = (short)f2h(p[kvb][2]);
      pw[3] = (short)f2h(p[kvb][3]);
      const int u = kvb * 2 + (gsl >> 1);
      *(short4v*)(Pw + ((u ^ arw7) << 4) + ((gsl & 1) << 3)) = pw;
    }
    __builtin_amdgcn_wave_barrier();
    short8 pa0 = *(const short8*)(Pw + ((gsl ^ arw7) << 4));
    short8 pa1 = *(const short8*)(Pw + (((4 + gsl) ^ arw7) << 4));
    __builtin_amdgcn_wave_barrier();

    short8 vf[4][2];
#pragma unroll
    for (int d = 0; d < 4; ++d) {
      int row = d * 16 + arow;
      int sw = (row & 7) << 4;
      vf[d][0] = *(const short8*)(vb + row * 128 + ((gsl * 16) ^ sw));
      vf[d][1] = *(const short8*)(vb + row * 128 + ((64 + gsl * 16) ^ sw));
    }
#pragma unroll
    for (int d = 0; d < 4; ++d) {
      o[d] = mfma16h(pa0, vf[d][0], o[d]);
      o[d] = mfma16h(pa1, vf[d][1], o[d]);
    }

    VMW0();
    BARR();
  }
#undef STAGEK
#undef STAGEV

  float amx = 0.f;
  float invl = 1.f / lrow;
  float invl_r[4];
#pragma unroll
  for (int r = 0; r < 4; ++r) invl_r[r] = __shfl(invl, gsl * 4 + r);
#pragma unroll
  for (int r = 0; r < 4; ++r) {
    size_t row = (size_t)(qr + gsl * 4 + r);
#pragma unroll
    for (int d = 0; d < 4; ++d) {
      float v = o[d][r] * invl_r[r];
      att[row * E_DIM + h * 64 + d * 16 + arow] = f2h(v);
      amx = fmaxf(amx, fabsf(v));
    }
  }

#pragma unroll
  for (int off = 32; off; off >>= 1) amx = fmaxf(amx, __shfl_xor(amx, off));
  if (ln == 0) atomicMax(amax + 3, __float_as_uint(amx));
}

// ---------------- act fake-quant f16 -> packed int8 (8 elems/thread) ----------------
__global__ void k_quant_act_i8(const unsigned short* __restrict__ in, uint2* __restrict__ out,
                               const unsigned* __restrict__ sc, int idx) {
  float scale = fmaxf(__uint_as_float(sc[idx]) * (1.f / 127.f), 1e-8f);
  float invs = 1.f / scale;
  int i = blockIdx.x * blockDim.x + threadIdx.x;
  short8 v = ((const short8*)in)[i];
  unsigned lo = 0, hi = 0;
#pragma unroll
  for (int e = 0; e < 4; ++e)
    lo |= (unsigned)(q8(h2f((unsigned short)v[e]), invs) & 255) << (8 * e);
#pragma unroll
  for (int e = 0; e < 4; ++e)
    hi |= (unsigned)(q8(h2f((unsigned short)v[4 + e]), invs) & 255) << (8 * e);
  uint2 pk; pk.x = lo; pk.y = hi;
  out[i] = pk;
}

extern "C" void kernel_launch(void* const* d_in, const int* in_sizes, int n_in,
                              void* d_out, int out_size, void* d_ws, size_t ws_size,
                              hipStream_t stream) {
  const float* hs = (const float*)d_in[0];
  const float* w_q = (const float*)d_in[1];
  const float* w_k = (const float*)d_in[2];
  const float* w_v = (const float*)d_in[3];
  const float* w_o = (const float*)d_in[4];

  char* ws = (char*)d_ws;
  unsigned short* wq_all = (unsigned short*)(ws);                 // 3 x E*E f16 (q,k,v)
  signed char* wo_i8 = (signed char*)(ws + 25165824);             // E*E i8
  float* wsc = (float*)(ws + 29360128);                           // 2048 f32
  float2* trig = (float2*)(ws + 30408704);                        // 65536 float2 (512KB)
  unsigned short* hsb = (unsigned short*)(ws + 33554432);         // S*E f16
  unsigned short* qkv16 = (unsigned short*)(ws + 41943040);       // 3 x S*E f16
  unsigned short* att = qkv16;                                    // alias q slab (f16)
  signed char* aq_i8 = (signed char*)(ws + 67108864);             // S*E i8
  unsigned short* Qh = (unsigned short*)(ws + 92274688);          // [H][S][D] f16
  unsigned short* Kh = (unsigned short*)(ws + 100663296);
  unsigned short* Vt = (unsigned short*)(ws + 109051904);         // [H][D][S] f16
  unsigned* sc = (unsigned*)(ws + 117440512);                     // absmax scalars

  k_prep<<<12545, 256, 0, stream>>>(hs, w_q, w_k, w_v, w_o, hsb, wq_all, wo_i8, wsc, sc, trig);
  k_gemm_qkv<<<dim3(192), 512, 0, stream>>>(hsb, wq_all, qkv16, sc, 0.125f);
  k_rvt<<<dim3(64, 32, 3), 256, 0, stream>>>(qkv16, Qh, Kh, Vt, sc, trig);
  k_attn<<<1024, 256, 0, stream>>>(Qh, Kh, Vt, att, sc);
  k_quant_act_i8<<<2048, 256, 0, stream>>>(att, (uint2*)aq_i8, sc, 3);
  k_gemm_o<<<dim3(16, 32), 256, 0, stream>>>(aq_i8, wo_i8, (float*)d_out, sc, wsc);
}

// Round 7
// 182.926 us; speedup vs baseline: 1.3133x; 1.0109x over previous
//
#include <hip/hip_runtime.h>
#include <hip/hip_bf16.h>
#include <hip/hip_fp16.h>

#define S_LEN 2048
#define E_DIM 2048
#define H_NUM 32
#define D_DIM 64

typedef __attribute__((ext_vector_type(8))) short short8;
typedef __attribute__((ext_vector_type(4))) short short4v;
typedef __attribute__((ext_vector_type(4))) float f32x4;
typedef __attribute__((ext_vector_type(4))) int i32x4;

__device__ __forceinline__ unsigned short f2h(float f) {
  return __builtin_bit_cast(unsigned short, (_Float16)f);
}

__device__ __forceinline__ float h2f(unsigned short u) {
  return (float)__builtin_bit_cast(_Float16, u);
}

__device__ __forceinline__ float fq1(float x, float invs, float scale) {
  return fminf(fmaxf(rintf(x * invs), -128.f), 127.f) * scale;
}

__device__ __forceinline__ int q8(float x, float invs) {
  return min(max((int)rintf(x * invs), -128), 127);
}

__device__ __forceinline__ void gload_lds16(const void* g, void* l) {
  __builtin_amdgcn_global_load_lds((const __attribute__((address_space(1))) void*)g,
                                   (__attribute__((address_space(3))) void*)l, 16, 0, 0);
}

__device__ __forceinline__ f32x4 mfma16h(short8 a, short8 b, f32x4 c) {
  return __builtin_amdgcn_mfma_f32_16x16x32_f16(a, b, c, 0, 0, 0);
}

__device__ __forceinline__ i32x4 mfma16i8(i32x4 a, i32x4 b, i32x4 c) {
  return __builtin_amdgcn_mfma_i32_16x16x64_i8(a, b, c, 0, 0, 0);
}

#define VMW4() asm volatile("s_waitcnt vmcnt(4)" ::: "memory")
#define VMW3() asm volatile("s_waitcnt vmcnt(3)" ::: "memory")
#define VMW0() asm volatile("s_waitcnt vmcnt(0)" ::: "memory")
#define BARR() asm volatile("s_barrier" ::: "memory")
#define LGKM0() asm volatile("s_waitcnt lgkmcnt(0)" ::: "memory")

// ========= merged prologue: cvt + quant_w + quant_wo + sc init + RoPE table =========
// blocks [0,4096): hs cvt; [4096,10240): w_{q,k,v}; [10240,12288): w_o->i8;
// b==12288: sc init; [12289,12545): cos/sin table (65536 (s,i) pairs, f32x2).
__global__ void k_prep(const float* __restrict__ hs,
                       const float* __restrict__ w_q, const float* __restrict__ w_k,
                       const float* __restrict__ w_v, const float* __restrict__ w_o,
                       unsigned short* __restrict__ hsb, unsigned short* __restrict__ wq_all,
                       signed char* __restrict__ wo_i8, float* __restrict__ wsc,
                       unsigned* __restrict__ sc, float2* __restrict__ trig) {
  const int b = blockIdx.x;
  if (b < 4096) {
    int i = b * 256 + threadIdx.x;
    float4 v = ((const float4*)hs)[i];
    ushort4 r;
    r.x = f2h(v.x); r.y = f2h(v.y); r.z = f2h(v.z); r.w = f2h(v.w);
    ((ushort4*)hsb)[i] = r;
    return;
  }
  if (b >= 12288) {
    if (b == 12288) {
      if (threadIdx.x < 8) sc[threadIdx.x] = 0u;
      return;
    }
    // trig table: idx = (b-12289)*256 + tid -> s = idx>>5, i = idx&31
    int idx = (b - 12289) * 256 + threadIdx.x;
    int s = idx >> 5, i = idx & 31;
    float freq = exp2f(-(float)i * (13.287712379549449f / 32.f));
    float ang = (float)s * freq;
    float sn, cs;
    sincosf(ang, &sn, &cs);
    float2 t; t.x = cs; t.y = sn;
    trig[idx] = t;
    return;
  }
  __shared__ float wm[4];
  const int isWo = (b >= 10240);
  const int bb = isWo ? (b - 10240) : (b - 4096);
  const int wy = isWo ? 0 : (bb >> 11);
  const int wx = isWo ? bb : (bb & 2047);
  const float* w = isWo ? w_o : (wy == 0 ? w_q : wy == 1 ? w_k : w_v);
  const float* row = w + (size_t)wx * E_DIM;
  float4 a = ((const float4*)row)[threadIdx.x * 2];
  float4 bq = ((const float4*)row)[threadIdx.x * 2 + 1];
  float m = fmaxf(fmaxf(fmaxf(fabsf(a.x), fabsf(a.y)), fmaxf(fabsf(a.z), fabsf(a.w))),
                  fmaxf(fmaxf(fabsf(bq.x), fabsf(bq.y)), fmaxf(fabsf(bq.z), fabsf(bq.w))));
#pragma unroll
  for (int off = 32; off; off >>= 1) m = fmaxf(m, __shfl_xor(m, off));
  if ((threadIdx.x & 63) == 0) wm[threadIdx.x >> 6] = m;
  __syncthreads();
  m = fmaxf(fmaxf(wm[0], wm[1]), fmaxf(wm[2], wm[3]));
  float scale = fmaxf(m * (1.f / 127.f), 1e-8f);
  float invs = 1.f / scale;
  if (isWo) {
    unsigned lo = (unsigned)(q8(a.x, invs) & 255) | ((unsigned)(q8(a.y, invs) & 255) << 8) |
                  ((unsigned)(q8(a.z, invs) & 255) << 16) | ((unsigned)(q8(a.w, invs) & 255) << 24);
    unsigned hi = (unsigned)(q8(bq.x, invs) & 255) | ((unsigned)(q8(bq.y, invs) & 255) << 8) |
                  ((unsigned)(q8(bq.z, invs) & 255) << 16) | ((unsigned)(q8(bq.w, invs) & 255) << 24);
    uint2 pk; pk.x = lo; pk.y = hi;
    ((uint2*)(wo_i8 + (size_t)wx * E_DIM))[threadIdx.x] = pk;
    if (threadIdx.x == 0) wsc[wx] = scale;
  } else {
    unsigned short* orow = wq_all + (size_t)wy * E_DIM * E_DIM + (size_t)wx * E_DIM;
    ushort4 r0, r1;
    r0.x = f2h(fq1(a.x, invs, scale)); r0.y = f2h(fq1(a.y, invs, scale));
    r0.z = f2h(fq1(a.z, invs, scale)); r0.w = f2h(fq1(a.w, invs, scale));
    r1.x = f2h(fq1(bq.x, invs, scale)); r1.y = f2h(fq1(bq.y, invs, scale));
    r1.z = f2h(fq1(bq.z, invs, scale)); r1.w = f2h(fq1(bq.w, invs, scale));
    ((ushort4*)orow)[threadIdx.x * 2] = r0;
    ((ushort4*)orow)[threadIdx.x * 2 + 1] = r1;
  }
}

// ========= 256x256 8-phase double-buffered f16 GEMM (QKV z-fused), XCD-swizzled ======
// PROVEN R0 version (76.2 us, MfmaUtil 27, FETCH 45MB): 512 threads = 8 waves
// (2M x 4N), BK=64 (2 K-steps/tile), LDS 128 KiB. Counted vmcnt(4) twice per
// K-tile (phases 2 and 4); every wait drains only loads issued >=2 phases ago.
__global__ __launch_bounds__(512, 2)
void k_gemm_qkv(const unsigned short* __restrict__ A, const unsigned short* __restrict__ Bt,
                unsigned short* __restrict__ C, unsigned* __restrict__ amax, float alpha_q) {
  __shared__ char lds[131072];
  const int K = 2048, NT = 32;
  // bijective XCD swizzle: 192 wgs, 192 % 8 == 0, 24 per XCD
  const int lin = blockIdx.x;
  const int swz = (lin & 7) * 24 + (lin >> 3);
  const int z = swz >> 6;
  const int t64 = swz & 63;
  const int iby = t64 >> 3;
  const int ibx = t64 & 7;
  const unsigned short* Bz = Bt + (size_t)z * E_DIM * E_DIM;
  unsigned short* Cz = C + (size_t)z * S_LEN * E_DIM;
  const float alpha = (z == 0) ? alpha_q : 1.0f;

  const int tid = threadIdx.x;
  const int wv = tid >> 6, ln = tid & 63;
  const int wm = wv >> 2, wn = wv & 3;
  const size_t bm = (size_t)ibx * 256, bn = (size_t)iby * 256;
  const int arow = ln & 15, gsl = ln >> 4;

  // LDS read byte offsets within one 64KB buffer (A: +s*16384; B: +32768+s*16384)
  int abyte[8], bbyte[4];
#pragma unroll
  for (int i = 0; i < 8; ++i) {
    int r = wm * 128 + i * 16 + arow;
    abyte[i] = r * 64 + ((gsl ^ ((r >> 1) & 3)) * 16);
  }
#pragma unroll
  for (int j = 0; j < 4; ++j) {
    int r = wn * 64 + j * 16 + arow;
    bbyte[j] = 32768 + r * 64 + ((gsl ^ ((r >> 1) & 3)) * 16);
  }

  // staging: thread tid covers rows (tid>>2) and (tid>>2)+128 of a 256x32 chunk;
  // pre-swizzled global source chunk so linear LDS dest + swizzled read agree
  const int srow = tid >> 2;
  const int scc = (tid & 3) ^ ((tid >> 3) & 3);
  const unsigned short* Asrc = A + (bm + srow) * (size_t)K + scc * 8;
  const unsigned short* Bsrc = Bz + (bn + srow) * (size_t)K + scc * 8;
  const int ldst = tid * 16;

#define STGA(T, S) do { \
    char* d_ = lds + ((T) & 1) * 65536 + (S) * 16384 + ldst; \
    const unsigned short* s_ = Asrc + (T) * 64 + (S) * 32; \
    gload_lds16(s_, d_); \
    gload_lds16(s_ + (size_t)128 * K, d_ + 8192); } while (0)
#define STGB(T, S) do { \
    char* d_ = lds + ((T) & 1) * 65536 + 32768 + (S) * 16384 + ldst; \
    const unsigned short* s_ = Bsrc + (T) * 64 + (S) * 32; \
    gload_lds16(s_, d_); \
    gload_lds16(s_ + (size_t)128 * K, d_ + 8192); } while (0)

  f32x4 acc[8][4];
#pragma unroll
  for (int i = 0; i < 8; ++i)
#pragma unroll
    for (int j = 0; j < 4; ++j) { acc[i][j][0] = 0.f; acc[i][j][1] = 0.f; acc[i][j][2] = 0.f; acc[i][j][3] = 0.f; }

  // prologue: tile 0 chunks (A-s0, B-s0, A-s1, B-s1); wait first two chunks
  STGA(0, 0); STGB(0, 0); STGA(0, 1); STGB(0, 1);
  VMW4();
  BARR();

  // One K-tile = 4 phases x 16 MFMA. DS: stage tile T1 into the other buffer.
  // W2X after phase-2 MFMA (guards this tile's s1 chunks), W4X after phase-4
  // MFMA (guards next tile's s0 chunks). Both vmcnt(4) in steady state.
#define TILE(BUF, DS, T1, W2X, W4X) do { \
    char* bp_ = lds + (BUF); \
    short8 af_[4], bf_[4], ag_[4]; \
    /* ---- phase 1: i0..3 x j0..3, k-step 0 ---- */ \
    _Pragma("unroll") for (int i = 0; i < 4; ++i) af_[i] = *(const short8*)(bp_ + abyte[i]); \
    _Pragma("unroll") for (int j = 0; j < 4; ++j) bf_[j] = *(const short8*)(bp_ + bbyte[j]); \
    if (DS) STGA(T1, 0); \
    BARR(); LGKM0(); \
    __builtin_amdgcn_s_setprio(1); \
    _Pragma("unroll") for (int i = 0; i < 4; ++i) \
      _Pragma("unroll") for (int j = 0; j < 4; ++j) acc[i][j] = mfma16h(af_[i], bf_[j], acc[i][j]); \
    __builtin_amdgcn_s_setprio(0); \
    BARR(); \
    /* ---- phase 2: i4..7 x j0..3, k-step 0 ---- */ \
    _Pragma("unroll") for (int i = 0; i < 4; ++i) ag_[i] = *(const short8*)(bp_ + abyte[4 + i]); \
    if (DS) STGB(T1, 0); \
    BARR(); LGKM0(); \
    __builtin_amdgcn_s_setprio(1); \
    _Pragma("unroll") for (int i = 0; i < 4; ++i) \
      _Pragma("unroll") for (int j = 0; j < 4; ++j) acc[4 + i][j] = mfma16h(ag_[i], bf_[j], acc[4 + i][j]); \
    __builtin_amdgcn_s_setprio(0); \
    W2X; \
    BARR(); \
    /* ---- phase 3: i0..3 x j0..3, k-step 1 ---- */ \
    _Pragma("unroll") for (int i = 0; i < 4; ++i) af_[i] = *(const short8*)(bp_ + 16384 + abyte[i]); \
    _Pragma("unroll") for (int j = 0; j < 4; ++j) bf_[j] = *(const short8*)(bp_ + 16384 + bbyte[j]); \
    if (DS) STGA(T1, 1); \
    BARR(); LGKM0(); \
    __builtin_amdgcn_s_setprio(1); \
    _Pragma("unroll") for (int i = 0; i < 4; ++i) \
      _Pragma("unroll") for (int j = 0; j < 4; ++j) acc[i][j] = mfma16h(af_[i], bf_[j], acc[i][j]); \
    __builtin_amdgcn_s_setprio(0); \
    BARR(); \
    /* ---- phase 4: i4..7 x j0..3, k-step 1 ---- */ \
    _Pragma("unroll") for (int i = 0; i < 4; ++i) ag_[i] = *(const short8*)(bp_ + 16384 + abyte[4 + i]); \
    if (DS) STGB(T1, 1); \
    BARR(); LGKM0(); \
    __builtin_amdgcn_s_setprio(1); \
    _Pragma("unroll") for (int i = 0; i < 4; ++i) \
      _Pragma("unroll") for (int j = 0; j < 4; ++j) acc[4 + i][j] = mfma16h(ag_[i], bf_[j], acc[4 + i][j]); \
    __builtin_amdgcn_s_setprio(0); \
    W4X; \
    BARR(); \
  } while (0)

#pragma unroll 1
  for (int t = 0; t < NT - 2; t += 2) {
    TILE(0, 1, t + 1, VMW4(), VMW4());
    TILE(65536, 1, t + 2, VMW4(), VMW4());
  }
  TILE(0, 1, NT - 1, VMW4(), VMW4());
  TILE(65536, 0, 0, VMW0(), (void)0);
#undef TILE
#undef STGA
#undef STGB

  float amx = 0.f;
#pragma unroll
  for (int i = 0; i < 8; ++i) {
    size_t rowb = bm + wm * 128 + i * 16 + gsl * 4;
#pragma unroll
    for (int j = 0; j < 4; ++j) {
      size_t col = bn + wn * 64 + j * 16 + arow;
#pragma unroll
      for (int r = 0; r < 4; ++r) {
        float v = acc[i][j][r] * alpha;
        Cz[(rowb + r) * E_DIM + col] = f2h(v);
        amx = fmaxf(amx, fabsf(v));
      }
    }
  }
#pragma unroll
  for (int off = 32; off; off >>= 1) amx = fmaxf(amx, __shfl_xor(amx, off));
  if (ln == 0) atomicMax(amax + z, __float_as_uint(amx));
}

// ========= o-proj: 128x64 tri-buffered INT8 GEMM, XCD-swizzled =========
__global__ __launch_bounds__(256, 4)
void k_gemm_o(const signed char* __restrict__ A, const signed char* __restrict__ Bt,
              float* __restrict__ C, const unsigned* __restrict__ sc,
              const float* __restrict__ wsc) {
  __shared__ char lds[36864];
  const int K = 2048, NT = 32;
  const float sa = fmaxf(__uint_as_float(sc[3]) * (1.f / 127.f), 1e-8f);
  const int lin = blockIdx.y * 16 + blockIdx.x;
  const int swz = (lin & 7) * 64 + (lin >> 3);
  const int iby = swz >> 4;
  const int ibx = swz & 15;

  const int tid = threadIdx.x;
  const int wv = tid >> 6, ln = tid & 63;
  const int wm = wv >> 1, wn = wv & 1;
  const size_t bm = (size_t)ibx * 128, bn = (size_t)iby * 64;
  const int arow = ln & 15, gsl = ln >> 4;

  int abyte[4], bbyte[2];
#pragma unroll
  for (int i = 0; i < 4; ++i) {
    int ra = wm * 64 + i * 16 + arow;
    abyte[i] = ra * 64 + ((gsl ^ ((ra >> 1) & 3)) * 16);
  }
#pragma unroll
  for (int j = 0; j < 2; ++j) {
    int rb = wn * 32 + j * 16 + arow;
    bbyte[j] = rb * 64 + ((gsl ^ ((rb >> 1) & 3)) * 16);
  }

  const int srow = tid >> 2;
  const int sl = (tid & 3) ^ ((srow >> 1) & 3);
  const signed char* Ast = A + (bm + srow) * (size_t)K + sl * 16;
  const signed char* Bst = Bt + (bn + srow) * (size_t)K + sl * 16;

#define STG(T, dst) do { if ((T) < NT) { \
    size_t go = (size_t)(T) * 64; \
    gload_lds16(Ast + go, (dst) + wv * 1024); \
    gload_lds16(Ast + go + (size_t)64 * K, (dst) + 4096 + wv * 1024); \
    gload_lds16(Bst + go, (dst) + 8192 + wv * 1024); } } while (0)

  i32x4 acc[4][2];
#pragma unroll
  for (int i = 0; i < 4; ++i)
#pragma unroll
    for (int j = 0; j < 2; ++j) { acc[i][j][0] = 0; acc[i][j][1] = 0; acc[i][j][2] = 0; acc[i][j][3] = 0; }

  char* b0 = lds;
  char* b1 = lds + 12288;
  char* b2 = lds + 24576;

  STG(0, b0); STG(1, b1);
  VMW3();
  BARR();

#define ITER(T, bufR, bufS) do { \
    i32x4 af[4], bf[2]; \
    _Pragma("unroll") \
    for (int i = 0; i < 4; ++i) af[i] = *(const i32x4*)((bufR) + abyte[i]); \
    _Pragma("unroll") \
    for (int j = 0; j < 2; ++j) bf[j] = *(const i32x4*)((bufR) + 8192 + bbyte[j]); \
    STG((T) + 2, bufS); \
    __builtin_amdgcn_s_setprio(1); \
    _Pragma("unroll") \
    for (int i = 0; i < 4; ++i) \
      _Pragma("unroll") \
      for (int j = 0; j < 2; ++j) acc[i][j] = mfma16i8(af[i], bf[j], acc[i][j]); \
    __builtin_amdgcn_s_setprio(0); \
    if ((T) == NT - 2) { VMW0(); } else if ((T) < NT - 2) { VMW3(); } \
    BARR(); } while (0)

#pragma unroll 1
  for (int t = 0; t + 2 < NT; t += 3) {
    ITER(t, b0, b2);
    ITER(t + 1, b1, b0);
    ITER(t + 2, b2, b1);
  }
  ITER(NT - 2, b0, b2);
  ITER(NT - 1, b1, b0);
#undef ITER
#undef STG

#pragma unroll
  for (int i = 0; i < 4; ++i) {
    size_t rowb = bm + wm * 64 + i * 16 + gsl * 4;
#pragma unroll
    for (int j = 0; j < 2; ++j) {
      size_t col = bn + wn * 32 + j * 16 + arow;
      float s = sa * wsc[col];
#pragma unroll
      for (int r = 0; r < 4; ++r)
        C[(rowb + r) * E_DIM + col] = (float)acc[i][j][r] * s;
    }
  }
}

// ========= merged RoPE(q,k, table-driven, VECTORIZED) + V-transpose (f16) =========
// q/k path (z<2): 64 blocks x 32 rows. Each thread owns 8 contiguous dims
// (one short8 load + one short8 store); rotate-half partner (i <-> i+32) comes
// from lane tid^4 via 4x shfl_xor (lanes j and j^4 hold the two halves of the
// same row). 8x fewer memory instructions than the scalar-2B version.
__global__ void k_rvt(const unsigned short* __restrict__ qkv,
                      unsigned short* __restrict__ Qh, unsigned short* __restrict__ Kh,
                      unsigned short* __restrict__ Vt, const unsigned* __restrict__ sc,
                      const float2* __restrict__ trig) {
  __shared__ float tb[64][65];
  const int z = blockIdx.z;
  if (z < 2) {
    const unsigned short* x = qkv + (z ? 4194304 : 0);
    unsigned short* out = z ? Kh : Qh;
    float scale = fmaxf(__uint_as_float(sc[z]) * (1.f / 127.f), 1e-8f);
    float invs = 1.f / scale;
    const int h = blockIdx.y;
    const int tid = threadIdx.x;
    const int s = blockIdx.x * 32 + (tid >> 3);
    const int j = tid & 7;
    // my 8 raw values: dims [j*8, j*8+8)
    short8 v = *(const short8*)(x + (size_t)s * E_DIM + h * 64 + j * 8);
    // partner (dims +-32): lane tid^4 (same row: tid>>3 unchanged)
    int pi[4];
    {
      const int* vi = (const int*)&v;
#pragma unroll
      for (int w = 0; w < 4; ++w) pi[w] = __shfl_xor(vi[w], 4);
    }
    short8 p = *(const short8*)pi;
    // out[i]    = q0*cos_i - q1*sin_i   (j<4: mine=q0, partner=q1)
    // out[i+32] = q1*cos_i + q0*sin_i   (j>=4: mine=q1, partner=q0)
    const float sgn = (j < 4) ? -1.f : 1.f;
    const float2* tp = trig + s * 32 + (j & 3) * 8;
    short8 ro;
#pragma unroll
    for (int e = 0; e < 8; ++e) {
      float me = fq1(h2f((unsigned short)v[e]), invs, scale);
      float pe = fq1(h2f((unsigned short)p[e]), invs, scale);
      float2 t = tp[e];
      ro[e] = (short)f2h(me * t.x + sgn * (pe * t.y));
    }
    *(short8*)(out + (size_t)h * S_LEN * D_DIM + (size_t)s * D_DIM + j * 8) = ro;
    return;
  }
  if (blockIdx.x >= 32) return;
  const unsigned short* v = qkv + 2 * 4194304;
  float scale = fmaxf(__uint_as_float(sc[2]) * (1.f / 127.f), 1e-8f);
  float invs = 1.f / scale;
  int s0 = blockIdx.x * 64, h = blockIdx.y;
#pragma unroll
  for (int l = 0; l < 16; ++l) {
    int idx = threadIdx.x + l * 256;
    int r = idx >> 6, c = idx & 63;
    float x = h2f(v[(size_t)(s0 + r) * E_DIM + h * 64 + c]);
    tb[r][c] = fq1(x, invs, scale);
  }
  __syncthreads();
#pragma unroll
  for (int l = 0; l < 16; ++l) {
    int idx = threadIdx.x + l * 256;
    int d = idx >> 6, s = idx & 63;
    Vt[(size_t)h * D_DIM * S_LEN + (size_t)d * S_LEN + s0 + s] = f2h(tb[s][d]);
  }
}

// -------- causal flash attention: 40KB LDS -> 4 blocks/CU (16 waves/CU) --------
// R6: load-balanced qc assignment. With 1024 blocks = exactly 4 resident/CU and
// in-order round-robin dispatch, CU c hosts blocks {c, c+256, c+512, c+768}.
// Mapping g=L>>5 -> qc via {31-p, p, 23-p, 8+p} (p=g&7, quartile g>>3) makes
// every CU's four nt values sum to 66 (was 56..84 -> makespan set by 84).
__global__ __launch_bounds__(256, 4)
void k_attn(const unsigned short* __restrict__ Qh, const unsigned short* __restrict__ Kh,
            const unsigned short* __restrict__ Vt, unsigned short* __restrict__ att,
            unsigned* __restrict__ amax) {
  __shared__ char Kbuf[2 * 8192];
  __shared__ char Vbuf[2 * 8192];
  __shared__ __align__(16) char Pb[8192];
  const int L = blockIdx.x;
  const int h = L & 31;
  const int g = L >> 5;
  const int p = g & 7, gg = g >> 3;
  const int qc = (gg == 0) ? (31 - p) : (gg == 1) ? p : (gg == 2) ? (23 - p) : (8 + p);
  const int nt = qc + 1;
  const int tid = threadIdx.x;
  const int wv = tid >> 6, ln = tid & 63;
  const int arow = ln & 15, gsl = ln >> 4;
  const unsigned short* Qb = Qh + (size_t)h * S_LEN * D_DIM;
  const unsigned short* Kb = Kh + (size_t)h * S_LEN * D_DIM;
  const unsigned short* Vb = Vt + (size_t)h * D_DIM * S_LEN;
  const int qr = qc * 64 + wv * 16;

  const int srow0 = tid >> 3, sch0 = (tid & 7) ^ (srow0 & 7);
  const int srow1 = 32 + (tid >> 3), sch1 = (tid & 7) ^ (srow1 & 7);

#define STAGEK(T, B) do { char* kd = Kbuf + (B) * 8192; const int tb_ = (T) * 64; \
    gload_lds16(Kb + (size_t)(tb_ + srow0) * D_DIM + sch0 * 8, kd + wv * 1024); \
    gload_lds16(Kb + (size_t)(tb_ + srow1) * D_DIM + sch1 * 8, kd + 4096 + wv * 1024); } while (0)
#define STAGEV(T, B) do { char* vd = Vbuf + (B) * 8192; const int tb_ = (T) * 64; \
    gload_lds16(Vb + (size_t)srow0 * S_LEN + tb_ + sch0 * 8, vd + wv * 1024); \
    gload_lds16(Vb + (size_t)srow1 * S_LEN + tb_ + sch1 * 8, vd + 4096 + wv * 1024); } while (0)

  short8 qa0 = *(const short8*)(Qb + (size_t)(qr + arow) * D_DIM + gsl * 8);
  short8 qa1 = *(const short8*)(Qb + (size_t)(qr + arow) * D_DIM + 32 + gsl * 8);

  f32x4 o[4];
  float mrow = -INFINITY, lrow = 0.f;
#pragma unroll
  for (int d = 0; d < 4; ++d) { o[d][0] = 0.f; o[d][1] = 0.f; o[d][2] = 0.f; o[d][3] = 0.f; }

  STAGEK(0, 0);
  STAGEV(0, 0);
  if (nt > 1) { STAGEK(1, 1); STAGEV(1, 1); VMW4(); } else { VMW0(); }
  BARR();

  char* Pw = Pb + wv * 2048 + arow * 128;
  const int arw7 = arow & 7;

#pragma unroll 1
  for (int t = 0; t < nt; ++t) {
    if (t >= 1 && t + 1 < nt) { STAGEK(t + 1, (t + 1) & 1); STAGEV(t + 1, (t + 1) & 1); }
    char* kb = Kbuf + (t & 1) * 8192;
    char* vb = Vbuf + (t & 1) * 8192;

    short8 kf[4][2];
#pragma unroll
    for (int kvb = 0; kvb < 4; ++kvb) {
      int row = kvb * 16 + arow;
      int sw = (row & 7) << 4;
      kf[kvb][0] = *(const short8*)(kb + row * 128 + ((gsl * 16) ^ sw));
      kf[kvb][1] = *(const short8*)(kb + row * 128 + ((64 + gsl * 16) ^ sw));
    }
    f32x4 s4[4];
#pragma unroll
    for (int kvb = 0; kvb < 4; ++kvb) {
      s4[kvb][0] = 0.f; s4[kvb][1] = 0.f; s4[kvb][2] = 0.f; s4[kvb][3] = 0.f;
    }
#pragma unroll
    for (int kvb = 0; kvb < 4; ++kvb) {
      s4[kvb] = mfma16h(kf[kvb][0], qa0, s4[kvb]);
      s4[kvb] = mfma16h(kf[kvb][1], qa1, s4[kvb]);
    }

    const int t0 = t * 64;
    const int qrow = qr + arow;
    if (t0 + 63 > qrow) {
#pragma unroll
      for (int kvb = 0; kvb < 4; ++kvb) {
        int colb = t0 + kvb * 16 + gsl * 4;
#pragma unroll
        for (int r = 0; r < 4; ++r)
          if (colb + r > qrow) s4[kvb][r] = -INFINITY;
      }
    }

    float smax = s4[0][0];
#pragma unroll
    for (int kvb = 0; kvb < 4; ++kvb)
#pragma unroll
      for (int r = 0; r < 4; ++r) smax = fmaxf(smax, s4[kvb][r]);
    smax = fmaxf(smax, __shfl_xor(smax, 16));
    smax = fmaxf(smax, __shfl_xor(smax, 32));

    float mn = fmaxf(mrow, smax);
    float corr = __expf(mrow - mn);
    mrow = mn;

    float rs = 0.f;
    float p4[4][4];
#pragma unroll
    for (int kvb = 0; kvb < 4; ++kvb)
#pragma unroll
      for (int r = 0; r < 4; ++r) {
        p4[kvb][r] = __expf(s4[kvb][r] - mn);
        rs += p4[kvb][r];
      }
    rs += __shfl_xor(rs, 16);
    rs += __shfl_xor(rs, 32);
    lrow = lrow * corr + rs;

    float corr_r[4];
#pragma unroll
    for (int r = 0; r < 4; ++r) corr_r[r] = __shfl(corr, gsl * 4 + r);
#pragma unroll
    for (int d = 0; d < 4; ++d)
#pragma unroll
      for (int r = 0; r < 4; ++r) o[d][r] *= corr_r[r];

    __builtin_amdgcn_wave_barrier();
#pragma unroll
    for (int kvb = 0; kvb < 4; ++kvb) {
      short4v pw;
      pw[0] = (short)f2h(p4[kvb][0]);
      pw[1] = (short)f2h(p4[kvb][1]);
      pw[2] = (short)f2h(p4[kvb][2]);
      pw[3] = (short)f2h(p4[kvb][3]);
      const int u = kvb * 2 + (gsl >> 1);
      *(short4v*)(Pw + ((u ^ arw7) << 4) + ((gsl & 1) << 3)) = pw;
    }
    __builtin_amdgcn_wave_barrier();
    short8 pa0 = *(const short8*)(Pw + ((gsl ^ arw7) << 4));
    short8 pa1 = *(const short8*)(Pw + (((4 + gsl) ^ arw7) << 4));
    __builtin_amdgcn_wave_barrier();

    short8 vf[4][2];
#pragma unroll
    for (int d = 0; d < 4; ++d) {
      int row = d * 16 + arow;
      int sw = (row & 7) << 4;
      vf[d][0] = *(const short8*)(vb + row * 128 + ((gsl * 16) ^ sw));
      vf[d][1] = *(const short8*)(vb + row * 128 + ((64 + gsl * 16) ^ sw));
    }
#pragma unroll
    for (int d = 0; d < 4; ++d) {
      o[d] = mfma16h(pa0, vf[d][0], o[d]);
      o[d] = mfma16h(pa1, vf[d][1], o[d]);
    }

    VMW0();
    BARR();
  }
#undef STAGEK
#undef STAGEV

  float amx = 0.f;
  float invl = 1.f / lrow;
  float invl_r[4];
#pragma unroll
  for (int r = 0; r < 4; ++r) invl_r[r] = __shfl(invl, gsl * 4 + r);
#pragma unroll
  for (int r = 0; r < 4; ++r) {
    size_t row = (size_t)(qr + gsl * 4 + r);
#pragma unroll
    for (int d = 0; d < 4; ++d) {
      float v = o[d][r] * invl_r[r];
      att[row * E_DIM + h * 64 + d * 16 + arow] = f2h(v);
      amx = fmaxf(amx, fabsf(v));
    }
  }

#pragma unroll
  for (int off = 32; off; off >>= 1) amx = fmaxf(amx, __shfl_xor(amx, off));
  if (ln == 0) atomicMax(amax + 3, __float_as_uint(amx));
}

// ---------------- act fake-quant f16 -> packed int8 (8 elems/thread) ----------------
__global__ void k_quant_act_i8(const unsigned short* __restrict__ in, uint2* __restrict__ out,
                               const unsigned* __restrict__ sc, int idx) {
  float scale = fmaxf(__uint_as_float(sc[idx]) * (1.f / 127.f), 1e-8f);
  float invs = 1.f / scale;
  int i = blockIdx.x * blockDim.x + threadIdx.x;
  short8 v = ((const short8*)in)[i];
  unsigned lo = 0, hi = 0;
#pragma unroll
  for (int e = 0; e < 4; ++e)
    lo |= (unsigned)(q8(h2f((unsigned short)v[e]), invs) & 255) << (8 * e);
#pragma unroll
  for (int e = 0; e < 4; ++e)
    hi |= (unsigned)(q8(h2f((unsigned short)v[4 + e]), invs) & 255) << (8 * e);
  uint2 pk; pk.x = lo; pk.y = hi;
  out[i] = pk;
}

extern "C" void kernel_launch(void* const* d_in, const int* in_sizes, int n_in,
                              void* d_out, int out_size, void* d_ws, size_t ws_size,
                              hipStream_t stream) {
  const float* hs = (const float*)d_in[0];
  const float* w_q = (const float*)d_in[1];
  const float* w_k = (const float*)d_in[2];
  const float* w_v = (const float*)d_in[3];
  const float* w_o = (const float*)d_in[4];

  char* ws = (char*)d_ws;
  unsigned short* wq_all = (unsigned short*)(ws);                 // 3 x E*E f16 (q,k,v)
  signed char* wo_i8 = (signed char*)(ws + 25165824);             // E*E i8
  float* wsc = (float*)(ws + 29360128);                           // 2048 f32
  float2* trig = (float2*)(ws + 30408704);                        // 65536 float2 (512KB)
  unsigned short* hsb = (unsigned short*)(ws + 33554432);         // S*E f16
  unsigned short* qkv16 = (unsigned short*)(ws + 41943040);       // 3 x S*E f16
  unsigned short* att = qkv16;                                    // alias q slab (f16)
  signed char* aq_i8 = (signed char*)(ws + 67108864);             // S*E i8
  unsigned short* Qh = (unsigned short*)(ws + 92274688);          // [H][S][D] f16
  unsigned short* Kh = (unsigned short*)(ws + 100663296);
  unsigned short* Vt = (unsigned short*)(ws + 109051904);         // [H][D][S] f16
  unsigned* sc = (unsigned*)(ws + 117440512);                     // absmax scalars

  k_prep<<<12545, 256, 0, stream>>>(hs, w_q, w_k, w_v, w_o, hsb, wq_all, wo_i8, wsc, sc, trig);
  k_gemm_qkv<<<dim3(192), 512, 0, stream>>>(hsb, wq_all, qkv16, sc, 0.125f);
  k_rvt<<<dim3(64, 32, 3), 256, 0, stream>>>(qkv16, Qh, Kh, Vt, sc, trig);
  k_attn<<<1024, 256, 0, stream>>>(Qh, Kh, Vt, att, sc);
  k_quant_act_i8<<<2048, 256, 0, stream>>>(att, (uint2*)aq_i8, sc, 3);
  k_gemm_o<<<dim3(16, 32), 256, 0, stream>>>(aq_i8, wo_i8, (float*)d_out, sc, wsc);
}